// Round 14
// baseline (1134.654 us; speedup 1.0000x reference)
//
#include <hip/hip_runtime.h>
#include <math.h>

#define N_NODES 51200
#define N_EDGES 409600
#define FEAT    768
#define HID     256
#define NPG     200
#define G_GRAPHS 256

typedef _Float16 f16x8 __attribute__((ext_vector_type(8)));
typedef _Float16 f16x4 __attribute__((ext_vector_type(4)));
typedef float    f32x4 __attribute__((ext_vector_type(4)));

__device__ __forceinline__ void cvt4(const float* __restrict__ in, _Float16* __restrict__ out, int i) {
    float4 v = *(const float4*)&in[i * 4];
    f16x4 h;
    h[0] = (_Float16)v.x; h[1] = (_Float16)v.y; h[2] = (_Float16)v.z; h[3] = (_Float16)v.w;
    *(f16x4*)&out[i * 4] = h;
}

// ---------------- mega prep: all elementwise prep in ONE launch (no XF anymore) ----------------
// segments: Win 49152 | Wih 49152 | Whh 49152 | Wg 98304 | wpack 49152 | bias 1024 |
// wcopyrz 786432 | zero-deg 12800 | zero-fill 12800   (total 1,107,968 -> grid 4328)
__global__ __launch_bounds__(256) void k_prep(const float* __restrict__ W_in, const float* __restrict__ W_ih,
                                              const float* __restrict__ W_hh, const float* __restrict__ W_g,
                                              const float* __restrict__ Wc1,
                                              const float* __restrict__ bih, const float* __restrict__ bhh,
                                              _Float16* __restrict__ Win_h, _Float16* __restrict__ Wih_h,
                                              _Float16* __restrict__ Whh_h, _Float16* __restrict__ Wg_h,
                                              _Float16* __restrict__ Wp,
                                              float* __restrict__ brz, float* __restrict__ bnn,
                                              _Float16* __restrict__ Wrz2,
                                              int* __restrict__ deg, int* __restrict__ fill) {
    int id = blockIdx.x * 256 + threadIdx.x;
    if (id < 49152) { cvt4(W_in, Win_h, id); return; }
    id -= 49152;
    if (id < 49152) { cvt4(W_ih, Wih_h, id); return; }
    id -= 49152;
    if (id < 49152) { cvt4(W_hh, Whh_h, id); return; }
    id -= 49152;
    if (id < 98304) { cvt4(W_g, Wg_h, id); return; }
    id -= 98304;
    if (id < 49152) {   // wpack: Wp[ch][o][dk*64+cc]
        int ch = id / 12288, r = id - ch * 12288;
        int o = r / 192, k = r - o * 192;
        int dk = k >> 6, cc = k & 63;
        int c = ch * 64 + cc;
        float v = 0.f;
        if (o < 50 && c < NPG) v = Wc1[(o * NPG + c) * 3 + dk];
        Wp[id] = (_Float16)v;
        return;
    }
    id -= 49152;
    if (id < 1024) {    // biases
        if (id < 512) brz[id] = bih[id] + bhh[id];
        else {
            int q = id - 512;
            bnn[q] = (q < 256) ? bih[512 + q] : bhh[512 + (q - 256)];
        }
        return;
    }
    id -= 1024;
    if (id < 786432) {  // Wrz2 right halves from fp32 W_hh: [l][j][256+c] = Whh[j][c]
        int l = id >> 17, r = id & 131071;
        int j = r >> 8, c = r & 255;
        Wrz2[(size_t)l * 262144 + j * 512 + 256 + c] = (_Float16)W_hh[j * 256 + c];
        return;
    }
    id -= 786432;
    if (id < 12800) { *(int4*)&deg[id * 4] = make_int4(0, 0, 0, 0); return; }
    id -= 12800;
    if (id < 12800) { *(int4*)&fill[id * 4] = make_int4(0, 0, 0, 0); return; }
}

// ---------------- CSR build ----------------
__global__ __launch_bounds__(256) void k_deg(const int* __restrict__ ei, int* __restrict__ deg) {
    int e = blockIdx.x * 256 + threadIdx.x;
    if (e < N_EDGES) atomicAdd(&deg[ei[N_EDGES + e]], 1);
}

__global__ __launch_bounds__(1024) void k_scan(const int* __restrict__ deg, int* __restrict__ rowp) {
    __shared__ int sums[1024];
    int tid = threadIdx.x;
    int base = tid * 50;
    int s = 0;
    for (int j = 0; j < 50; ++j) s += deg[base + j];
    sums[tid] = s;
    __syncthreads();
    for (int off = 1; off < 1024; off <<= 1) {
        int v = 0;
        if (tid >= off) v = sums[tid - off];
        __syncthreads();
        sums[tid] += v;
        __syncthreads();
    }
    int run = sums[tid] - s; // exclusive prefix
    for (int j = 0; j < 50; ++j) { rowp[base + j] = run; run += deg[base + j]; }
    if (tid == 1023) rowp[N_NODES] = run;
}

__global__ __launch_bounds__(256) void k_fill(const int* __restrict__ ei, const int* __restrict__ rowp,
                                              int* __restrict__ fill, int* __restrict__ col) {
    int e = blockIdx.x * 256 + threadIdx.x;
    if (e < N_EDGES) {
        int d = ei[N_EDGES + e];
        int pos = atomicAdd(&fill[d], 1);
        col[rowp[d] + pos] = ei[e];
    }
}

// ---------------- fp16 MFMA GEMM (NT): C[M,*] = A[M,K] @ B_f16[J,K]^T + bias ----------------
template<int AF16, int OUT, int COLB, int SWZ>
__global__ __launch_bounds__(256) void k_gemm2(const void* __restrict__ Av, int lda,
                                               const _Float16* __restrict__ B,
                                               const float* __restrict__ bias,
                                               void* __restrict__ Cv, int ldc,
                                               int K, int wgPerL, int aLStride, int bLStride,
                                               int cLStride, int biasStride) {
    __shared__ _Float16 As[128 * 64];
    __shared__ _Float16 Bs[128 * 64];
    int wg = blockIdx.x;
    int l = wg / wgPerL; wg -= l * wgPerL;
    if (AF16) Av = (const void*)((const _Float16*)Av + (size_t)l * aLStride);
    else      Av = (const void*)((const float*)Av + (size_t)l * aLStride);
    B += (size_t)l * bLStride;
    if (bias) bias += (size_t)l * biasStride;
    if (OUT == 1) Cv = (void*)((_Float16*)Cv + (size_t)l * cLStride);
    else          Cv = (void*)((float*)Cv + (size_t)l * cLStride);
    int rowBase, colBase;
    if (SWZ) {
        int xcd = wg & 7, t = wg >> 3;
        int cb = t % COLB, gidx = t / COLB;
        rowBase = (gidx * 8 + xcd) * 128;
        colBase = cb * 128;
    } else {
        rowBase = (wg / COLB) * 128;
        colBase = (wg % COLB) * 128;
    }
    int tid = threadIdx.x;
    int lane = tid & 63;
    int wid = tid >> 6;
    int wr = wid >> 1, wc = wid & 1;
    f32x4 acc[4][4] = {};
    for (int k0 = 0; k0 < K; k0 += 64) {
        __syncthreads();
        #pragma unroll
        for (int p = 0; p < 4; ++p) {
            int c = p * 256 + tid;
            int row = c >> 3, slot = c & 7;
            int dst = row * 64 + ((slot ^ (row & 7)) * 8);
            if (AF16) {
                const _Float16* srcA = (const _Float16*)Av + (size_t)(rowBase + row) * lda + k0 + slot * 8;
                *(f16x8*)&As[dst] = *(const f16x8*)srcA;
            } else {
                const float* srcA = (const float*)Av + (size_t)(rowBase + row) * lda + k0 + slot * 8;
                float4 f0 = *(const float4*)srcA;
                float4 f1 = *(const float4*)(srcA + 4);
                f16x8 hv;
                hv[0] = (_Float16)f0.x; hv[1] = (_Float16)f0.y; hv[2] = (_Float16)f0.z; hv[3] = (_Float16)f0.w;
                hv[4] = (_Float16)f1.x; hv[5] = (_Float16)f1.y; hv[6] = (_Float16)f1.z; hv[7] = (_Float16)f1.w;
                *(f16x8*)&As[dst] = hv;
            }
            const _Float16* srcB = B + (size_t)(colBase + row) * K + k0 + slot * 8;
            *(f16x8*)&Bs[dst] = *(const f16x8*)srcB;
        }
        __syncthreads();
        #pragma unroll
        for (int ks = 0; ks < 2; ++ks) {
            f16x8 af[4], bf[4];
            #pragma unroll
            for (int mi = 0; mi < 4; ++mi) {
                int row = wr * 64 + mi * 16 + (lane & 15);
                int slot = (lane >> 4) + ks * 4;
                af[mi] = *(const f16x8*)&As[row * 64 + ((slot ^ (row & 7)) * 8)];
            }
            #pragma unroll
            for (int nj = 0; nj < 4; ++nj) {
                int row = wc * 64 + nj * 16 + (lane & 15);
                int slot = (lane >> 4) + ks * 4;
                bf[nj] = *(const f16x8*)&Bs[row * 64 + ((slot ^ (row & 7)) * 8)];
            }
            #pragma unroll
            for (int mi = 0; mi < 4; ++mi)
                #pragma unroll
                for (int nj = 0; nj < 4; ++nj)
                    acc[mi][nj] = __builtin_amdgcn_mfma_f32_16x16x32_f16(af[mi], bf[nj], acc[mi][nj], 0, 0, 0);
        }
    }
    #pragma unroll
    for (int mi = 0; mi < 4; ++mi) {
        #pragma unroll
        for (int nj = 0; nj < 4; ++nj) {
            int col = colBase + wc * 64 + nj * 16 + (lane & 15);
            float bv = bias ? bias[col] : 0.f;
            #pragma unroll
            for (int r = 0; r < 4; ++r) {
                int row = rowBase + wr * 64 + mi * 16 + (lane >> 4) * 4 + r;
                float val = acc[mi][nj][r] + bv;
                if (OUT == 0) ((float*)Cv)[(size_t)row * ldc + col] = val;
                else          ((_Float16*)Cv)[(size_t)row * ldc + col] = (_Float16)val;
            }
        }
    }
}

// ---------------- rz GEMM: RZ[N,512] = [S|hc] @ Wrz2_l^T + brz (K=512, dual-A) ----------------
__global__ __launch_bounds__(256) void k_gemmrz(const _Float16* __restrict__ S, const _Float16* __restrict__ hc,
                                                const _Float16* __restrict__ B, const float* __restrict__ bias,
                                                _Float16* __restrict__ C) {
    __shared__ _Float16 As[128 * 64];
    __shared__ _Float16 Bs[128 * 64];
    int wg = blockIdx.x;                 // 1600 = 8 * 4 * 50
    int xcd = wg & 7, t = wg >> 3;
    int cb = t % 4, gidx = t / 4;
    int rowBase = (gidx * 8 + xcd) * 128;
    int colBase = cb * 128;
    int tid = threadIdx.x;
    int lane = tid & 63;
    int wid = tid >> 6;
    int wr = wid >> 1, wc = wid & 1;
    f32x4 acc[4][4] = {};
    for (int k0 = 0; k0 < 512; k0 += 64) {
        const _Float16* Abase = (k0 < 256) ? S : hc;
        int kk = k0 & 255;
        __syncthreads();
        #pragma unroll
        for (int p = 0; p < 4; ++p) {
            int c = p * 256 + tid;
            int row = c >> 3, slot = c & 7;
            int dst = row * 64 + ((slot ^ (row & 7)) * 8);
            *(f16x8*)&As[dst] = *(const f16x8*)&Abase[(size_t)(rowBase + row) * 256 + kk + slot * 8];
            *(f16x8*)&Bs[dst] = *(const f16x8*)&B[(size_t)(colBase + row) * 512 + k0 + slot * 8];
        }
        __syncthreads();
        #pragma unroll
        for (int ks = 0; ks < 2; ++ks) {
            f16x8 af[4], bf[4];
            #pragma unroll
            for (int mi = 0; mi < 4; ++mi) {
                int row = wr * 64 + mi * 16 + (lane & 15);
                int slot = (lane >> 4) + ks * 4;
                af[mi] = *(const f16x8*)&As[row * 64 + ((slot ^ (row & 7)) * 8)];
            }
            #pragma unroll
            for (int nj = 0; nj < 4; ++nj) {
                int row = wc * 64 + nj * 16 + (lane & 15);
                int slot = (lane >> 4) + ks * 4;
                bf[nj] = *(const f16x8*)&Bs[row * 64 + ((slot ^ (row & 7)) * 8)];
            }
            #pragma unroll
            for (int mi = 0; mi < 4; ++mi)
                #pragma unroll
                for (int nj = 0; nj < 4; ++nj)
                    acc[mi][nj] = __builtin_amdgcn_mfma_f32_16x16x32_f16(af[mi], bf[nj], acc[mi][nj], 0, 0, 0);
        }
    }
    #pragma unroll
    for (int mi = 0; mi < 4; ++mi) {
        #pragma unroll
        for (int nj = 0; nj < 4; ++nj) {
            int col = colBase + wc * 64 + nj * 16 + (lane & 15);
            float bv = bias[col];
            #pragma unroll
            for (int r = 0; r < 4; ++r) {
                int row = rowBase + wr * 64 + mi * 16 + (lane >> 4) * 4 + r;
                C[(size_t)row * 512 + col] = (_Float16)(acc[mi][nj][r] + bv);
            }
        }
    }
}

// ---------------- fused n-gate GEMMs + GRU ----------------
__global__ __launch_bounds__(512) void k_nngru(const _Float16* __restrict__ S, const _Float16* __restrict__ hc,
                                               const _Float16* __restrict__ B0, const _Float16* __restrict__ B1,
                                               const float* __restrict__ bnn, const _Float16* __restrict__ rz,
                                               _Float16* __restrict__ hn) {
    __shared__ _Float16 As0[128 * 64], As1[128 * 64], Bs0[128 * 64], Bs1[128 * 64];
    int wg = blockIdx.x;                 // 800 = 8 * 2 * 50
    int xcd = wg & 7, t = wg >> 3;
    int cb = t % 2, gidx = t / 2;
    int rowBase = (gidx * 8 + xcd) * 128;
    int colBase = cb * 128;
    int tid = threadIdx.x;
    int lane = tid & 63;
    int wid = tid >> 6;
    int wr = wid >> 2, wc = wid & 3;
    f32x4 acc0[4][2] = {}, acc1[4][2] = {};
    for (int k0 = 0; k0 < 256; k0 += 64) {
        __syncthreads();
        #pragma unroll
        for (int p = 0; p < 8; ++p) {
            int q = p * 512 + tid;
            int tile = q >> 10;
            int c = q & 1023;
            int row = c >> 3, slot = c & 7;
            int dst = row * 64 + ((slot ^ (row & 7)) * 8);
            const _Float16* src;
            _Float16* d;
            if (tile == 0)      { src = S  + (size_t)(rowBase + row) * 256 + k0 + slot * 8; d = As0; }
            else if (tile == 1) { src = hc + (size_t)(rowBase + row) * 256 + k0 + slot * 8; d = As1; }
            else if (tile == 2) { src = B0 + (size_t)(colBase + row) * 256 + k0 + slot * 8; d = Bs0; }
            else                { src = B1 + (size_t)(colBase + row) * 256 + k0 + slot * 8; d = Bs1; }
            *(f16x8*)&d[dst] = *(const f16x8*)src;
        }
        __syncthreads();
        #pragma unroll
        for (int ks = 0; ks < 2; ++ks) {
            f16x8 a0[4], a1[4], b0[2], b1[2];
            #pragma unroll
            for (int mi = 0; mi < 4; ++mi) {
                int row = wr * 64 + mi * 16 + (lane & 15);
                int slot = (lane >> 4) + ks * 4;
                int off = row * 64 + ((slot ^ (row & 7)) * 8);
                a0[mi] = *(const f16x8*)&As0[off];
                a1[mi] = *(const f16x8*)&As1[off];
            }
            #pragma unroll
            for (int nj = 0; nj < 2; ++nj) {
                int row = wc * 32 + nj * 16 + (lane & 15);
                int slot = (lane >> 4) + ks * 4;
                int off = row * 64 + ((slot ^ (row & 7)) * 8);
                b0[nj] = *(const f16x8*)&Bs0[off];
                b1[nj] = *(const f16x8*)&Bs1[off];
            }
            #pragma unroll
            for (int mi = 0; mi < 4; ++mi)
                #pragma unroll
                for (int nj = 0; nj < 2; ++nj) {
                    acc0[mi][nj] = __builtin_amdgcn_mfma_f32_16x16x32_f16(a0[mi], b0[nj], acc0[mi][nj], 0, 0, 0);
                    acc1[mi][nj] = __builtin_amdgcn_mfma_f32_16x16x32_f16(a1[mi], b1[nj], acc1[mi][nj], 0, 0, 0);
                }
        }
    }
    #pragma unroll
    for (int mi = 0; mi < 4; ++mi) {
        #pragma unroll
        for (int nj = 0; nj < 2; ++nj) {
            int col = colBase + wc * 32 + nj * 16 + (lane & 15);
            float bi = bnn[col], bh = bnn[256 + col];
            #pragma unroll
            for (int r = 0; r < 4; ++r) {
                int row = rowBase + wr * 64 + mi * 16 + (lane >> 4) * 4 + r;
                float rv = (float)rz[(size_t)row * 512 + col];
                float zv = (float)rz[(size_t)row * 512 + 256 + col];
                float rg = 1.f / (1.f + expf(-rv));
                float zg = 1.f / (1.f + expf(-zv));
                float ng = tanhf((acc0[mi][nj][r] + bi) + rg * (acc1[mi][nj][r] + bh));
                float ho = (float)hc[(size_t)row * 256 + col];
                hn[(size_t)row * 256 + col] = (_Float16)((1.f - zg) * ng + zg * ho);
            }
        }
    }
}

// ---------------- gather-sum of hc into S (32 lanes/node, f16x8 loads, unroll 4) ----------------
__global__ __launch_bounds__(256) void k_agg5(const int* __restrict__ rowp, const int* __restrict__ col,
                                              const _Float16* __restrict__ hc, _Float16* __restrict__ S) {
    int v = blockIdx.x * 8 + (threadIdx.x >> 5);
    int lane = threadIdx.x & 31;
    int beg = rowp[v], end = rowp[v + 1];
    const _Float16* hf = hc + lane * 8;
    float a0 = 0.f, a1 = 0.f, a2 = 0.f, a3 = 0.f, a4 = 0.f, a5 = 0.f, a6 = 0.f, a7 = 0.f;
    int i = beg;
    for (; i + 3 < end; i += 4) {
        int c0 = col[i], c1 = col[i + 1], c2 = col[i + 2], c3 = col[i + 3];
        f16x8 u0 = *(const f16x8*)&hf[(size_t)c0 * 256];
        f16x8 u1 = *(const f16x8*)&hf[(size_t)c1 * 256];
        f16x8 u2 = *(const f16x8*)&hf[(size_t)c2 * 256];
        f16x8 u3 = *(const f16x8*)&hf[(size_t)c3 * 256];
        a0 += ((float)u0[0] + (float)u1[0]) + ((float)u2[0] + (float)u3[0]);
        a1 += ((float)u0[1] + (float)u1[1]) + ((float)u2[1] + (float)u3[1]);
        a2 += ((float)u0[2] + (float)u1[2]) + ((float)u2[2] + (float)u3[2]);
        a3 += ((float)u0[3] + (float)u1[3]) + ((float)u2[3] + (float)u3[3]);
        a4 += ((float)u0[4] + (float)u1[4]) + ((float)u2[4] + (float)u3[4]);
        a5 += ((float)u0[5] + (float)u1[5]) + ((float)u2[5] + (float)u3[5]);
        a6 += ((float)u0[6] + (float)u1[6]) + ((float)u2[6] + (float)u3[6]);
        a7 += ((float)u0[7] + (float)u1[7]) + ((float)u2[7] + (float)u3[7]);
    }
    for (; i < end; ++i) {
        f16x8 u = *(const f16x8*)&hf[(size_t)col[i] * 256];
        a0 += (float)u[0]; a1 += (float)u[1]; a2 += (float)u[2]; a3 += (float)u[3];
        a4 += (float)u[4]; a5 += (float)u[5]; a6 += (float)u[6]; a7 += (float)u[7];
    }
    f16x8 o;
    o[0] = (_Float16)a0; o[1] = (_Float16)a1; o[2] = (_Float16)a2; o[3] = (_Float16)a3;
    o[4] = (_Float16)a4; o[5] = (_Float16)a5; o[6] = (_Float16)a6; o[7] = (_Float16)a7;
    *(f16x8*)&S[(size_t)v * 256 + lane * 8] = o;
}

// ---------------- conv1 as MFMA implicit GEMM, merged Z+Y; x read fp32 directly ----------------
__global__ __launch_bounds__(256, 2) void k_conv1m(const _Float16* __restrict__ hf, const float* __restrict__ xf,
                                                   const _Float16* __restrict__ Wp, const float* __restrict__ bc1,
                                                   float* __restrict__ outZ, float* __restrict__ outY) {
    __shared__ _Float16 XT[272 * 64];
    __shared__ _Float16 WL[64 * 192];
    int b = blockIdx.x;
    int g, t0, H;
    float* out;
    if (b < 1024) { g = b >> 2; t0 = (b & 3) * 256; H = 1024; out = outZ; }
    else          { g = b - 1024; t0 = 0; H = 256; out = outY; }
    int tid = threadIdx.x;
    int lane = tid & 63;
    int wn = (tid >> 6) * 64;
    f32x4 acc[4][4] = {};
    for (int ch = 0; ch < 4; ++ch) {
        __syncthreads();
        #pragma unroll
        for (int i = 0; i < 6; ++i) {
            int q = i * 256 + tid;
            int o = q / 24, sk = q - o * 24;
            int skp = (sk & 0x18) | ((sk & 7) ^ (o & 7));
            *(f16x8*)&WL[o * 192 + skp * 8] = *(const f16x8*)&Wp[ch * 12288 + o * 192 + sk * 8];
        }
        for (int u = tid; u < 272; u += 256) {
            int r8 = u / 34, pc = u - r8 * 34;
            int gstart = t0 - 8 + pc * 8;
            int c0 = r8 * 8;
            f16x8 zv;
            #pragma unroll
            for (int q = 0; q < 8; ++q) zv[q] = (_Float16)0.f;
            f16x8 rows[8];
            if (gstart < 0 || gstart >= H) {
                #pragma unroll
                for (int j = 0; j < 8; ++j) rows[j] = zv;
            } else if (gstart < HID) {
                const _Float16* base = hf + gstart;
                int node0 = g * NPG + ch * 64 + c0;
                #pragma unroll
                for (int j = 0; j < 8; ++j) {
                    int cg = ch * 64 + c0 + j;
                    rows[j] = (cg < NPG) ? *(const f16x8*)&base[(size_t)(node0 + j) * 256] : zv;
                }
            } else {
                const float* base = xf + (gstart - HID);
                int node0 = g * NPG + ch * 64 + c0;
                #pragma unroll
                for (int j = 0; j < 8; ++j) {
                    int cg = ch * 64 + c0 + j;
                    if (cg < NPG) {
                        const float* rp = base + (size_t)(node0 + j) * FEAT;
                        float4 f0 = *(const float4*)rp;
                        float4 f1 = *(const float4*)(rp + 4);
                        f16x8 hv;
                        hv[0] = (_Float16)f0.x; hv[1] = (_Float16)f0.y; hv[2] = (_Float16)f0.z; hv[3] = (_Float16)f0.w;
                        hv[4] = (_Float16)f1.x; hv[5] = (_Float16)f1.y; hv[6] = (_Float16)f1.z; hv[7] = (_Float16)f1.w;
                        rows[j] = hv;
                    } else rows[j] = zv;
                }
            }
            #pragma unroll
            for (int jj = 0; jj < 8; ++jj) {
                f16x8 w;
                #pragma unroll
                for (int j = 0; j < 8; ++j) w[j] = rows[j][jj];
                int p = pc * 8 + jj;
                int slot = r8 ^ jj ^ (pc & 7);
                *(f16x8*)&XT[p * 64 + slot * 8] = w;
            }
        }
        __syncthreads();
        #pragma unroll
        for (int ks = 0; ks < 6; ++ks) {
            int dk = ks >> 1, cs0 = (ks & 1) << 2;
            f16x8 af[4], bf[4];
            #pragma unroll
            for (int mi = 0; mi < 4; ++mi) {
                int o = mi * 16 + (lane & 15);
                int sk = ks * 4 + (lane >> 4);
                int skp = (sk & 0x18) | ((sk & 7) ^ (o & 7));
                af[mi] = *(const f16x8*)&WL[o * 192 + skp * 8];
            }
            #pragma unroll
            for (int nj = 0; nj < 4; ++nj) {
                int tw = wn + nj * 16 + (lane & 15) + dk + 7;
                int sp = (cs0 + (lane >> 4)) ^ (tw & 7) ^ ((tw >> 3) & 7);
                bf[nj] = *(const f16x8*)&XT[tw * 64 + sp * 8];
            }
            #pragma unroll
            for (int mi = 0; mi < 4; ++mi)
                #pragma unroll
                for (int nj = 0; nj < 4; ++nj)
                    acc[mi][nj] = __builtin_amdgcn_mfma_f32_16x16x32_f16(af[mi], bf[nj], acc[mi][nj], 0, 0, 0);
        }
    }
    #pragma unroll
    for (int mi = 0; mi < 4; ++mi) {
        #pragma unroll
        for (int r = 0; r < 4; ++r) {
            int o = mi * 16 + (lane >> 4) * 4 + r;
            if (o < 50) {
                float bv = bc1[o];
                #pragma unroll
                for (int nj = 0; nj < 4; ++nj) {
                    int t = t0 + wn + nj * 16 + (lane & 15);
                    float v = acc[mi][nj][r] + bv;
                    out[(size_t)g * 50 * H + (size_t)o * H + t] = v > 0.f ? v : 0.f;
                }
            }
        }
    }
}

// ---------------- maxpool1d k=3 s=2, merged Z+Y ----------------
__global__ __launch_bounds__(256) void k_pool1(const float* __restrict__ C1Z, const float* __restrict__ C1Y,
                                               float* __restrict__ P1Z, float* __restrict__ P1Y) {
    int b = blockIdx.x;
    const float* in;
    float* out;
    int H, U, go;
    if (b < 12800) { in = C1Z; out = P1Z; H = 1024; U = 511; go = b; }
    else           { in = C1Y; out = P1Y; H = 256;  U = 127; go = b - 12800; }
    const float* p = in + (size_t)go * H;
    float* q = out + (size_t)go * U;
    for (int u = threadIdx.x; u < U; u += 256) {
        float a = p[2 * u], bb = p[2 * u + 1], c = p[2 * u + 2];
        float mm = a > bb ? a : bb;
        q[u] = mm > c ? mm : c;
    }
}

// ---------------- conv2(k=1)+pool(k2s2)+FC+final, ONE block per graph ----------------
__global__ __launch_bounds__(256) void k_c2fc(const float* __restrict__ P1Z, const float* __restrict__ P1Y,
                                              const float* __restrict__ Wc2, const float* __restrict__ bc2,
                                              const float* __restrict__ Wf1, const float* __restrict__ bf1,
                                              const float* __restrict__ Wf2, const float* __restrict__ bf2,
                                              float* __restrict__ out) {
    __shared__ float wL[20][52];
    __shared__ float red[256];
    int g = blockIdx.x, tid = threadIdx.x;
    for (int l = tid; l < 1000; l += 256) wL[l / 50][l % 50] = Wc2[l];
    __syncthreads();
    // ---- Z path (U=511, U2=255) ----
    float s = 0.f;
    if (tid < 255) {
        const float* p = P1Z + (size_t)g * 50 * 511 + 2 * tid;
        float a0[20], a1[20];
        #pragma unroll
        for (int o = 0; o < 20; ++o) { a0[o] = bc2[o]; a1[o] = a0[o]; }
        for (int i = 0; i < 50; ++i) {
            float p0 = p[(size_t)i * 511], p1 = p[(size_t)i * 511 + 1];
            #pragma unroll
            for (int o = 0; o < 20; ++o) {
                a0[o] = fmaf(p0, wL[o][i], a0[o]);
                a1[o] = fmaf(p1, wL[o][i], a1[o]);
            }
        }
        #pragma unroll
        for (int o = 0; o < 20; ++o) {
            float m = a0[o] > a1[o] ? a0[o] : a1[o];
            s = fmaf(m, Wf1[o * 255 + tid], s);
        }
    }
    red[tid] = s;
    __syncthreads();
    for (int off = 128; off > 0; off >>= 1) {
        if (tid < off) red[tid] += red[tid + off];
        __syncthreads();
    }
    float zv = red[0] + bf1[0];
    __syncthreads();
    // ---- Y path (U=127, U2=63) ----
    s = 0.f;
    if (tid < 63) {
        const float* p = P1Y + (size_t)g * 50 * 127 + 2 * tid;
        float a0[20], a1[20];
        #pragma unroll
        for (int o = 0; o < 20; ++o) { a0[o] = bc2[o]; a1[o] = a0[o]; }
        for (int i = 0; i < 50; ++i) {
            float p0 = p[(size_t)i * 127], p1 = p[(size_t)i * 127 + 1];
            #pragma unroll
            for (int o = 0; o < 20; ++o) {
                a0[o] = fmaf(p0, wL[o][i], a0[o]);
                a1[o] = fmaf(p1, wL[o][i], a1[o]);
            }
        }
        #pragma unroll
        for (int o = 0; o < 20; ++o) {
            float m = a0[o] > a1[o] ? a0[o] : a1[o];
            s = fmaf(m, Wf2[o * 63 + tid], s);
        }
    }
    red[tid] = s;
    __syncthreads();
    for (int off = 128; off > 0; off >>= 1) {
        if (tid < off) red[tid] += red[tid + off];
        __syncthreads();
    }
    if (tid == 0) {
        float yv = red[0] + bf2[0];
        float t = zv * yv;
        float pp = 1.f / (1.f + expf(-t));
        pp = fminf(fmaxf(pp, 1e-6f), 1.f - 1e-6f);
        out[2 * g] = 0.f;
        out[2 * g + 1] = logf(pp / (1.f - pp));
    }
}

extern "C" void kernel_launch(void* const* d_in, const int* in_sizes, int n_in,
                              void* d_out, int out_size, void* d_ws, size_t ws_size,
                              hipStream_t stream) {
    const float* x     = (const float*)d_in[0];
    const int*   ei    = (const int*)d_in[1];
    const float* W_in  = (const float*)d_in[2];
    const float* b_in  = (const float*)d_in[3];
    const float* W_g   = (const float*)d_in[4];
    const float* W_ih  = (const float*)d_in[5];
    const float* W_hh  = (const float*)d_in[6];
    const float* b_ih  = (const float*)d_in[7];
    const float* b_hh  = (const float*)d_in[8];
    const float* Wc1   = (const float*)d_in[9];
    const float* bc1   = (const float*)d_in[10];
    const float* Wc2   = (const float*)d_in[11];
    const float* bc2   = (const float*)d_in[12];
    const float* Wf1   = (const float*)d_in[13];
    const float* bf1   = (const float*)d_in[14];
    const float* Wf2   = (const float*)d_in[15];
    const float* bf2   = (const float*)d_in[16];

    float* ws = (float*)d_ws;
    // layout (float units) — unchanged from rounds 10-13 (verified); XF region now DEAD.
    const size_t OFF_S   = 0;           // S  f16 [N,256] -> 6,553,600
    const size_t OFF_HA  = 6553600;     // HA f16 [N,256] -> 13,107,200
    const size_t OFF_HB  = 13107200;    // HB f16 [N,256] -> 19,660,800
    const size_t OFF_RZ  = 19660800;    // RZ f16 [N,512] -> 32,768,000
    // OFF_XF 32,768,000..52,428,800 now unused
    const size_t OFF_WF  = 52428800;    // f16 arena 2,998,272 f16 -> 53,927,936
    const size_t OFF_BRZ = 53927936;    // [512]
    const size_t OFF_BNN = 53928448;    // [512]
    const size_t OFF_INT = 53928960;    // ints 563,201 -> 54,492,161

    _Float16* S  = (_Float16*)(ws + OFF_S);
    _Float16* HA = (_Float16*)(ws + OFF_HA);
    _Float16* HB = (_Float16*)(ws + OFF_HB);
    _Float16* RZ = (_Float16*)(ws + OFF_RZ);

    _Float16* Win_h = (_Float16*)(ws + OFF_WF);  // [256][768] = 196,608
    _Float16* Wih_h = Win_h + 196608;            // [768][256]
    _Float16* Whh_h = Wih_h + 196608;            // [768][256]
    _Float16* Wg_h  = Whh_h + 196608;            // [6][256][256] = 393,216
    _Float16* Wrz2  = Wg_h  + 393216;            // [6][512][512] = 1,572,864
    _Float16* Wni2  = Wrz2  + 1572864;           // [6][256][256] = 393,216
    _Float16* Wp    = Wni2  + 393216;            // [4][64][192] = 49,152
    _Float16* Whhn  = Whh_h + 512 * 256;         // Whh rows 512..767
    float* brz = ws + OFF_BRZ;
    float* bnn = ws + OFF_BNN;

    int* deg  = (int*)(ws + OFF_INT);
    int* fill = deg + N_NODES;
    int* rowp = fill + N_NODES;
    int* col  = rowp + (N_NODES + 1);

    // conv-phase scratch in DEAD regions (live then: HA, weights, ints):
    float* C1Z = ws + OFF_RZ;            // 13,107,200 -> ends 32,768,000
    float* P1Z = ws + OFF_HB;            // 6,540,800  -> ends 19,648,000 (< OFF_RZ)
    float* C1Y = ws + OFF_S;             // 3,276,800
    float* P1Y = ws + 3300000;           // 1,625,600  -> ends 4,925,600 (< OFF_HA)

    // ---- mega prep (all elementwise prep + deg/fill zeroing, ONE launch) ----
    k_prep<<<4328, 256, 0, stream>>>(W_in, W_ih, W_hh, W_g, Wc1, b_ih, b_hh,
                                     Win_h, Wih_h, Whh_h, Wg_h, Wp, brz, bnn, Wrz2,
                                     deg, fill);
    // fold Wg: Wrz2[l][:, :256] = Wih[0:512] @ Wg[l]^T ; Wni2[l] = Wih[512:768] @ Wg[l]^T
    k_gemm2<1, 1, 2, 0><<<48, 256, 0, stream>>>(Wih_h, 256, Wg_h, nullptr,
                                                Wrz2, 512, 256, 8, 0, 65536, 262144, 0);
    k_gemm2<1, 1, 2, 0><<<24, 256, 0, stream>>>(Wih_h + 512 * 256, 256, Wg_h, nullptr,
                                                Wni2, 256, 256, 4, 0, 65536, 65536, 0);

    // ---- CSR build ----
    k_deg<<<N_EDGES / 256, 256, 0, stream>>>(ei, deg);
    k_scan<<<1, 1024, 0, stream>>>(deg, rowp);
    k_fill<<<N_EDGES / 256, 256, 0, stream>>>(ei, rowp, fill, col);

    // ---- h0 = x @ W_in^T + b_in -> HA (f16); A read fp32 directly (identical rounding) ----
    k_gemm2<0, 1, 2, 1><<<800, 256, 0, stream>>>(x, FEAT, Win_h, b_in, HA, HID,
                                                 FEAT, 800, 0, 0, 0, 0);

    // ---- GGNN layers (h ping-pongs HA <-> HB; ends in HA) ----
    for (int l = 0; l < 6; ++l) {
        _Float16* hc = (l & 1) ? HB : HA;
        _Float16* hn = (l & 1) ? HA : HB;
        k_agg5<<<6400, 256, 0, stream>>>(rowp, col, hc, S);
        k_gemmrz<<<1600, 256, 0, stream>>>(S, hc, Wrz2 + (size_t)l * 262144, brz, RZ);
        k_nngru<<<800, 512, 0, stream>>>(S, hc, Wni2 + (size_t)l * 65536, Whhn, bnn, RZ, hn);
    }

    // ---- conv head ----
    k_conv1m<<<1280, 256, 0, stream>>>(HA, x, Wp, bc1, C1Z, C1Y);
    k_pool1<<<25600, 256, 0, stream>>>(C1Z, C1Y, P1Z, P1Y);
    k_c2fc<<<G_GRAPHS, 256, 0, stream>>>(P1Z, P1Y, Wc2, bc2, Wf1, bf1, Wf2, bf2, (float*)d_out);
}

// Round 15
// 1101.891 us; speedup vs baseline: 1.0297x; 1.0297x over previous
//
#include <hip/hip_runtime.h>
#include <math.h>

#define N_NODES 51200
#define N_EDGES 409600
#define FEAT    768
#define HID     256
#define NPG     200
#define G_GRAPHS 256

typedef _Float16 f16x8 __attribute__((ext_vector_type(8)));
typedef _Float16 f16x4 __attribute__((ext_vector_type(4)));
typedef float    f32x4 __attribute__((ext_vector_type(4)));

__device__ __forceinline__ void cvt4(const float* __restrict__ in, _Float16* __restrict__ out, int i) {
    float4 v = *(const float4*)&in[i * 4];
    f16x4 h;
    h[0] = (_Float16)v.x; h[1] = (_Float16)v.y; h[2] = (_Float16)v.z; h[3] = (_Float16)v.w;
    *(f16x4*)&out[i * 4] = h;
}

// ---------------- mega prep: all elementwise prep in ONE launch (incl. x->XF) ----------------
// segments: Win 49152 | Wih 49152 | Whh 49152 | Wg 98304 | wpack 49152 | bias 1024 |
// wcopyrz 786432 | zero-deg 12800 | zero-fill 12800 | x->XF 9830400  (total 10,938,368 -> grid 42728)
__global__ __launch_bounds__(256) void k_prep(const float* __restrict__ W_in, const float* __restrict__ W_ih,
                                              const float* __restrict__ W_hh, const float* __restrict__ W_g,
                                              const float* __restrict__ x, const float* __restrict__ Wc1,
                                              const float* __restrict__ bih, const float* __restrict__ bhh,
                                              _Float16* __restrict__ Win_h, _Float16* __restrict__ Wih_h,
                                              _Float16* __restrict__ Whh_h, _Float16* __restrict__ Wg_h,
                                              _Float16* __restrict__ XF, _Float16* __restrict__ Wp,
                                              float* __restrict__ brz, float* __restrict__ bnn,
                                              _Float16* __restrict__ Wrz2,
                                              int* __restrict__ deg, int* __restrict__ fill) {
    int id = blockIdx.x * 256 + threadIdx.x;
    if (id < 49152) { cvt4(W_in, Win_h, id); return; }
    id -= 49152;
    if (id < 49152) { cvt4(W_ih, Wih_h, id); return; }
    id -= 49152;
    if (id < 49152) { cvt4(W_hh, Whh_h, id); return; }
    id -= 49152;
    if (id < 98304) { cvt4(W_g, Wg_h, id); return; }
    id -= 98304;
    if (id < 49152) {   // wpack: Wp[ch][o][dk*64+cc]
        int ch = id / 12288, r = id - ch * 12288;
        int o = r / 192, k = r - o * 192;
        int dk = k >> 6, cc = k & 63;
        int c = ch * 64 + cc;
        float v = 0.f;
        if (o < 50 && c < NPG) v = Wc1[(o * NPG + c) * 3 + dk];
        Wp[id] = (_Float16)v;
        return;
    }
    id -= 49152;
    if (id < 1024) {    // biases
        if (id < 512) brz[id] = bih[id] + bhh[id];
        else {
            int q = id - 512;
            bnn[q] = (q < 256) ? bih[512 + q] : bhh[512 + (q - 256)];
        }
        return;
    }
    id -= 1024;
    if (id < 786432) {  // Wrz2 right halves from fp32 W_hh: [l][j][256+c] = Whh[j][c]
        int l = id >> 17, r = id & 131071;
        int j = r >> 8, c = r & 255;
        Wrz2[(size_t)l * 262144 + j * 512 + 256 + c] = (_Float16)W_hh[j * 256 + c];
        return;
    }
    id -= 786432;
    if (id < 12800) { *(int4*)&deg[id * 4] = make_int4(0, 0, 0, 0); return; }
    id -= 12800;
    if (id < 12800) { *(int4*)&fill[id * 4] = make_int4(0, 0, 0, 0); return; }
    id -= 12800;
    if (id < 9830400) { cvt4(x, XF, id); return; }
}

// ---------------- CSR build ----------------
__global__ __launch_bounds__(256) void k_deg(const int* __restrict__ ei, int* __restrict__ deg) {
    int e = blockIdx.x * 256 + threadIdx.x;
    if (e < N_EDGES) atomicAdd(&deg[ei[N_EDGES + e]], 1);
}

__global__ __launch_bounds__(1024) void k_scan(const int* __restrict__ deg, int* __restrict__ rowp) {
    __shared__ int sums[1024];
    int tid = threadIdx.x;
    int base = tid * 50;
    int s = 0;
    for (int j = 0; j < 50; ++j) s += deg[base + j];
    sums[tid] = s;
    __syncthreads();
    for (int off = 1; off < 1024; off <<= 1) {
        int v = 0;
        if (tid >= off) v = sums[tid - off];
        __syncthreads();
        sums[tid] += v;
        __syncthreads();
    }
    int run = sums[tid] - s; // exclusive prefix
    for (int j = 0; j < 50; ++j) { rowp[base + j] = run; run += deg[base + j]; }
    if (tid == 1023) rowp[N_NODES] = run;
}

__global__ __launch_bounds__(256) void k_fill(const int* __restrict__ ei, const int* __restrict__ rowp,
                                              int* __restrict__ fill, int* __restrict__ col) {
    int e = blockIdx.x * 256 + threadIdx.x;
    if (e < N_EDGES) {
        int d = ei[N_EDGES + e];
        int pos = atomicAdd(&fill[d], 1);
        col[rowp[d] + pos] = ei[e];
    }
}

// ---------------- fp16 MFMA GEMM (NT): C[M,*] = A[M,K] @ B_f16[J,K]^T + bias ----------------
template<int AF16, int OUT, int COLB, int SWZ>
__global__ __launch_bounds__(256) void k_gemm2(const void* __restrict__ Av, int lda,
                                               const _Float16* __restrict__ B,
                                               const float* __restrict__ bias,
                                               void* __restrict__ Cv, int ldc,
                                               int K, int wgPerL, int aLStride, int bLStride,
                                               int cLStride, int biasStride) {
    __shared__ _Float16 As[128 * 64];
    __shared__ _Float16 Bs[128 * 64];
    int wg = blockIdx.x;
    int l = wg / wgPerL; wg -= l * wgPerL;
    if (AF16) Av = (const void*)((const _Float16*)Av + (size_t)l * aLStride);
    else      Av = (const void*)((const float*)Av + (size_t)l * aLStride);
    B += (size_t)l * bLStride;
    if (bias) bias += (size_t)l * biasStride;
    if (OUT == 1) Cv = (void*)((_Float16*)Cv + (size_t)l * cLStride);
    else          Cv = (void*)((float*)Cv + (size_t)l * cLStride);
    int rowBase, colBase;
    if (SWZ) {
        int xcd = wg & 7, t = wg >> 3;
        int cb = t % COLB, gidx = t / COLB;
        rowBase = (gidx * 8 + xcd) * 128;
        colBase = cb * 128;
    } else {
        rowBase = (wg / COLB) * 128;
        colBase = (wg % COLB) * 128;
    }
    int tid = threadIdx.x;
    int lane = tid & 63;
    int wid = tid >> 6;
    int wr = wid >> 1, wc = wid & 1;
    f32x4 acc[4][4] = {};
    for (int k0 = 0; k0 < K; k0 += 64) {
        __syncthreads();
        #pragma unroll
        for (int p = 0; p < 4; ++p) {
            int c = p * 256 + tid;
            int row = c >> 3, slot = c & 7;
            int dst = row * 64 + ((slot ^ (row & 7)) * 8);
            if (AF16) {
                const _Float16* srcA = (const _Float16*)Av + (size_t)(rowBase + row) * lda + k0 + slot * 8;
                *(f16x8*)&As[dst] = *(const f16x8*)srcA;
            } else {
                const float* srcA = (const float*)Av + (size_t)(rowBase + row) * lda + k0 + slot * 8;
                float4 f0 = *(const float4*)srcA;
                float4 f1 = *(const float4*)(srcA + 4);
                f16x8 hv;
                hv[0] = (_Float16)f0.x; hv[1] = (_Float16)f0.y; hv[2] = (_Float16)f0.z; hv[3] = (_Float16)f0.w;
                hv[4] = (_Float16)f1.x; hv[5] = (_Float16)f1.y; hv[6] = (_Float16)f1.z; hv[7] = (_Float16)f1.w;
                *(f16x8*)&As[dst] = hv;
            }
            const _Float16* srcB = B + (size_t)(colBase + row) * K + k0 + slot * 8;
            *(f16x8*)&Bs[dst] = *(const f16x8*)srcB;
        }
        __syncthreads();
        #pragma unroll
        for (int ks = 0; ks < 2; ++ks) {
            f16x8 af[4], bf[4];
            #pragma unroll
            for (int mi = 0; mi < 4; ++mi) {
                int row = wr * 64 + mi * 16 + (lane & 15);
                int slot = (lane >> 4) + ks * 4;
                af[mi] = *(const f16x8*)&As[row * 64 + ((slot ^ (row & 7)) * 8)];
            }
            #pragma unroll
            for (int nj = 0; nj < 4; ++nj) {
                int row = wc * 64 + nj * 16 + (lane & 15);
                int slot = (lane >> 4) + ks * 4;
                bf[nj] = *(const f16x8*)&Bs[row * 64 + ((slot ^ (row & 7)) * 8)];
            }
            #pragma unroll
            for (int mi = 0; mi < 4; ++mi)
                #pragma unroll
                for (int nj = 0; nj < 4; ++nj)
                    acc[mi][nj] = __builtin_amdgcn_mfma_f32_16x16x32_f16(af[mi], bf[nj], acc[mi][nj], 0, 0, 0);
        }
    }
    #pragma unroll
    for (int mi = 0; mi < 4; ++mi) {
        #pragma unroll
        for (int nj = 0; nj < 4; ++nj) {
            int col = colBase + wc * 64 + nj * 16 + (lane & 15);
            float bv = bias ? bias[col] : 0.f;
            #pragma unroll
            for (int r = 0; r < 4; ++r) {
                int row = rowBase + wr * 64 + mi * 16 + (lane >> 4) * 4 + r;
                float val = acc[mi][nj][r] + bv;
                if (OUT == 0) ((float*)Cv)[(size_t)row * ldc + col] = val;
                else          ((_Float16*)Cv)[(size_t)row * ldc + col] = (_Float16)val;
            }
        }
    }
}

// ---------------- rz GEMM: RZ[N,512] = [S|hc] @ Wrz2_l^T + brz (K=512, dual-A) ----------------
__global__ __launch_bounds__(256) void k_gemmrz(const _Float16* __restrict__ S, const _Float16* __restrict__ hc,
                                                const _Float16* __restrict__ B, const float* __restrict__ bias,
                                                _Float16* __restrict__ C) {
    __shared__ _Float16 As[128 * 64];
    __shared__ _Float16 Bs[128 * 64];
    int wg = blockIdx.x;                 // 1600 = 8 * 4 * 50
    int xcd = wg & 7, t = wg >> 3;
    int cb = t % 4, gidx = t / 4;
    int rowBase = (gidx * 8 + xcd) * 128;
    int colBase = cb * 128;
    int tid = threadIdx.x;
    int lane = tid & 63;
    int wid = tid >> 6;
    int wr = wid >> 1, wc = wid & 1;
    f32x4 acc[4][4] = {};
    for (int k0 = 0; k0 < 512; k0 += 64) {
        const _Float16* Abase = (k0 < 256) ? S : hc;
        int kk = k0 & 255;
        __syncthreads();
        #pragma unroll
        for (int p = 0; p < 4; ++p) {
            int c = p * 256 + tid;
            int row = c >> 3, slot = c & 7;
            int dst = row * 64 + ((slot ^ (row & 7)) * 8);
            *(f16x8*)&As[dst] = *(const f16x8*)&Abase[(size_t)(rowBase + row) * 256 + kk + slot * 8];
            *(f16x8*)&Bs[dst] = *(const f16x8*)&B[(size_t)(colBase + row) * 512 + k0 + slot * 8];
        }
        __syncthreads();
        #pragma unroll
        for (int ks = 0; ks < 2; ++ks) {
            f16x8 af[4], bf[4];
            #pragma unroll
            for (int mi = 0; mi < 4; ++mi) {
                int row = wr * 64 + mi * 16 + (lane & 15);
                int slot = (lane >> 4) + ks * 4;
                af[mi] = *(const f16x8*)&As[row * 64 + ((slot ^ (row & 7)) * 8)];
            }
            #pragma unroll
            for (int nj = 0; nj < 4; ++nj) {
                int row = wc * 64 + nj * 16 + (lane & 15);
                int slot = (lane >> 4) + ks * 4;
                bf[nj] = *(const f16x8*)&Bs[row * 64 + ((slot ^ (row & 7)) * 8)];
            }
            #pragma unroll
            for (int mi = 0; mi < 4; ++mi)
                #pragma unroll
                for (int nj = 0; nj < 4; ++nj)
                    acc[mi][nj] = __builtin_amdgcn_mfma_f32_16x16x32_f16(af[mi], bf[nj], acc[mi][nj], 0, 0, 0);
        }
    }
    #pragma unroll
    for (int mi = 0; mi < 4; ++mi) {
        #pragma unroll
        for (int nj = 0; nj < 4; ++nj) {
            int col = colBase + wc * 64 + nj * 16 + (lane & 15);
            float bv = bias[col];
            #pragma unroll
            for (int r = 0; r < 4; ++r) {
                int row = rowBase + wr * 64 + mi * 16 + (lane >> 4) * 4 + r;
                C[(size_t)row * 512 + col] = (_Float16)(acc[mi][nj][r] + bv);
            }
        }
    }
}

// ---------------- fused n-gate GEMMs + GRU ----------------
__global__ __launch_bounds__(512) void k_nngru(const _Float16* __restrict__ S, const _Float16* __restrict__ hc,
                                               const _Float16* __restrict__ B0, const _Float16* __restrict__ B1,
                                               const float* __restrict__ bnn, const _Float16* __restrict__ rz,
                                               _Float16* __restrict__ hn) {
    __shared__ _Float16 As0[128 * 64], As1[128 * 64], Bs0[128 * 64], Bs1[128 * 64];
    int wg = blockIdx.x;                 // 800 = 8 * 2 * 50
    int xcd = wg & 7, t = wg >> 3;
    int cb = t % 2, gidx = t / 2;
    int rowBase = (gidx * 8 + xcd) * 128;
    int colBase = cb * 128;
    int tid = threadIdx.x;
    int lane = tid & 63;
    int wid = tid >> 6;
    int wr = wid >> 2, wc = wid & 3;
    f32x4 acc0[4][2] = {}, acc1[4][2] = {};
    for (int k0 = 0; k0 < 256; k0 += 64) {
        __syncthreads();
        #pragma unroll
        for (int p = 0; p < 8; ++p) {
            int q = p * 512 + tid;
            int tile = q >> 10;
            int c = q & 1023;
            int row = c >> 3, slot = c & 7;
            int dst = row * 64 + ((slot ^ (row & 7)) * 8);
            const _Float16* src;
            _Float16* d;
            if (tile == 0)      { src = S  + (size_t)(rowBase + row) * 256 + k0 + slot * 8; d = As0; }
            else if (tile == 1) { src = hc + (size_t)(rowBase + row) * 256 + k0 + slot * 8; d = As1; }
            else if (tile == 2) { src = B0 + (size_t)(colBase + row) * 256 + k0 + slot * 8; d = Bs0; }
            else                { src = B1 + (size_t)(colBase + row) * 256 + k0 + slot * 8; d = Bs1; }
            *(f16x8*)&d[dst] = *(const f16x8*)src;
        }
        __syncthreads();
        #pragma unroll
        for (int ks = 0; ks < 2; ++ks) {
            f16x8 a0[4], a1[4], b0[2], b1[2];
            #pragma unroll
            for (int mi = 0; mi < 4; ++mi) {
                int row = wr * 64 + mi * 16 + (lane & 15);
                int slot = (lane >> 4) + ks * 4;
                int off = row * 64 + ((slot ^ (row & 7)) * 8);
                a0[mi] = *(const f16x8*)&As0[off];
                a1[mi] = *(const f16x8*)&As1[off];
            }
            #pragma unroll
            for (int nj = 0; nj < 2; ++nj) {
                int row = wc * 32 + nj * 16 + (lane & 15);
                int slot = (lane >> 4) + ks * 4;
                int off = row * 64 + ((slot ^ (row & 7)) * 8);
                b0[nj] = *(const f16x8*)&Bs0[off];
                b1[nj] = *(const f16x8*)&Bs1[off];
            }
            #pragma unroll
            for (int mi = 0; mi < 4; ++mi)
                #pragma unroll
                for (int nj = 0; nj < 2; ++nj) {
                    acc0[mi][nj] = __builtin_amdgcn_mfma_f32_16x16x32_f16(a0[mi], b0[nj], acc0[mi][nj], 0, 0, 0);
                    acc1[mi][nj] = __builtin_amdgcn_mfma_f32_16x16x32_f16(a1[mi], b1[nj], acc1[mi][nj], 0, 0, 0);
                }
        }
    }
    #pragma unroll
    for (int mi = 0; mi < 4; ++mi) {
        #pragma unroll
        for (int nj = 0; nj < 2; ++nj) {
            int col = colBase + wc * 32 + nj * 16 + (lane & 15);
            float bi = bnn[col], bh = bnn[256 + col];
            #pragma unroll
            for (int r = 0; r < 4; ++r) {
                int row = rowBase + wr * 64 + mi * 16 + (lane >> 4) * 4 + r;
                float rv = (float)rz[(size_t)row * 512 + col];
                float zv = (float)rz[(size_t)row * 512 + 256 + col];
                float rg = 1.f / (1.f + expf(-rv));
                float zg = 1.f / (1.f + expf(-zv));
                float ng = tanhf((acc0[mi][nj][r] + bi) + rg * (acc1[mi][nj][r] + bh));
                float ho = (float)hc[(size_t)row * 256 + col];
                hn[(size_t)row * 256 + col] = (_Float16)((1.f - zg) * ng + zg * ho);
            }
        }
    }
}

// ---------------- gather-sum of hc into S (32 lanes/node, f16x8 loads, unroll 4) ----------------
__global__ __launch_bounds__(256) void k_agg5(const int* __restrict__ rowp, const int* __restrict__ col,
                                              const _Float16* __restrict__ hc, _Float16* __restrict__ S) {
    int v = blockIdx.x * 8 + (threadIdx.x >> 5);
    int lane = threadIdx.x & 31;
    int beg = rowp[v], end = rowp[v + 1];
    const _Float16* hf = hc + lane * 8;
    float a0 = 0.f, a1 = 0.f, a2 = 0.f, a3 = 0.f, a4 = 0.f, a5 = 0.f, a6 = 0.f, a7 = 0.f;
    int i = beg;
    for (; i + 3 < end; i += 4) {
        int c0 = col[i], c1 = col[i + 1], c2 = col[i + 2], c3 = col[i + 3];
        f16x8 u0 = *(const f16x8*)&hf[(size_t)c0 * 256];
        f16x8 u1 = *(const f16x8*)&hf[(size_t)c1 * 256];
        f16x8 u2 = *(const f16x8*)&hf[(size_t)c2 * 256];
        f16x8 u3 = *(const f16x8*)&hf[(size_t)c3 * 256];
        a0 += ((float)u0[0] + (float)u1[0]) + ((float)u2[0] + (float)u3[0]);
        a1 += ((float)u0[1] + (float)u1[1]) + ((float)u2[1] + (float)u3[1]);
        a2 += ((float)u0[2] + (float)u1[2]) + ((float)u2[2] + (float)u3[2]);
        a3 += ((float)u0[3] + (float)u1[3]) + ((float)u2[3] + (float)u3[3]);
        a4 += ((float)u0[4] + (float)u1[4]) + ((float)u2[4] + (float)u3[4]);
        a5 += ((float)u0[5] + (float)u1[5]) + ((float)u2[5] + (float)u3[5]);
        a6 += ((float)u0[6] + (float)u1[6]) + ((float)u2[6] + (float)u3[6]);
        a7 += ((float)u0[7] + (float)u1[7]) + ((float)u2[7] + (float)u3[7]);
    }
    for (; i < end; ++i) {
        f16x8 u = *(const f16x8*)&hf[(size_t)col[i] * 256];
        a0 += (float)u[0]; a1 += (float)u[1]; a2 += (float)u[2]; a3 += (float)u[3];
        a4 += (float)u[4]; a5 += (float)u[5]; a6 += (float)u[6]; a7 += (float)u[7];
    }
    f16x8 o;
    o[0] = (_Float16)a0; o[1] = (_Float16)a1; o[2] = (_Float16)a2; o[3] = (_Float16)a3;
    o[4] = (_Float16)a4; o[5] = (_Float16)a5; o[6] = (_Float16)a6; o[7] = (_Float16)a7;
    *(f16x8*)&S[(size_t)v * 256 + lane * 8] = o;
}

// ---------------- conv1 as MFMA implicit GEMM, merged Z+Y launch (f16 inputs) ----------------
__global__ __launch_bounds__(256, 2) void k_conv1m(const _Float16* __restrict__ hf, const _Float16* __restrict__ xf,
                                                   const _Float16* __restrict__ Wp, const float* __restrict__ bc1,
                                                   float* __restrict__ outZ, float* __restrict__ outY) {
    __shared__ _Float16 XT[272 * 64];
    __shared__ _Float16 WL[64 * 192];
    int b = blockIdx.x;
    int g, t0, H;
    float* out;
    if (b < 1024) { g = b >> 2; t0 = (b & 3) * 256; H = 1024; out = outZ; }
    else          { g = b - 1024; t0 = 0; H = 256; out = outY; }
    int tid = threadIdx.x;
    int lane = tid & 63;
    int wn = (tid >> 6) * 64;
    f32x4 acc[4][4] = {};
    for (int ch = 0; ch < 4; ++ch) {
        __syncthreads();
        #pragma unroll
        for (int i = 0; i < 6; ++i) {
            int q = i * 256 + tid;
            int o = q / 24, sk = q - o * 24;
            int skp = (sk & 0x18) | ((sk & 7) ^ (o & 7));
            *(f16x8*)&WL[o * 192 + skp * 8] = *(const f16x8*)&Wp[ch * 12288 + o * 192 + sk * 8];
        }
        for (int u = tid; u < 272; u += 256) {
            int r8 = u / 34, pc = u - r8 * 34;
            int gstart = t0 - 8 + pc * 8;
            int c0 = r8 * 8;
            f16x8 zv;
            #pragma unroll
            for (int q = 0; q < 8; ++q) zv[q] = (_Float16)0.f;
            f16x8 rows[8];
            if (gstart < 0 || gstart >= H) {
                #pragma unroll
                for (int j = 0; j < 8; ++j) rows[j] = zv;
            } else {
                const _Float16* base;
                int stride;
                if (gstart < HID) { base = hf + gstart; stride = 256; }
                else              { base = xf + (gstart - HID); stride = 768; }
                int node0 = g * NPG + ch * 64 + c0;
                #pragma unroll
                for (int j = 0; j < 8; ++j) {
                    int cg = ch * 64 + c0 + j;
                    rows[j] = (cg < NPG) ? *(const f16x8*)&base[(size_t)(node0 + j) * stride] : zv;
                }
            }
            #pragma unroll
            for (int jj = 0; jj < 8; ++jj) {
                f16x8 w;
                #pragma unroll
                for (int j = 0; j < 8; ++j) w[j] = rows[j][jj];
                int p = pc * 8 + jj;
                int slot = r8 ^ jj ^ (pc & 7);
                *(f16x8*)&XT[p * 64 + slot * 8] = w;
            }
        }
        __syncthreads();
        #pragma unroll
        for (int ks = 0; ks < 6; ++ks) {
            int dk = ks >> 1, cs0 = (ks & 1) << 2;
            f16x8 af[4], bf[4];
            #pragma unroll
            for (int mi = 0; mi < 4; ++mi) {
                int o = mi * 16 + (lane & 15);
                int sk = ks * 4 + (lane >> 4);
                int skp = (sk & 0x18) | ((sk & 7) ^ (o & 7));
                af[mi] = *(const f16x8*)&WL[o * 192 + skp * 8];
            }
            #pragma unroll
            for (int nj = 0; nj < 4; ++nj) {
                int tw = wn + nj * 16 + (lane & 15) + dk + 7;
                int sp = (cs0 + (lane >> 4)) ^ (tw & 7) ^ ((tw >> 3) & 7);
                bf[nj] = *(const f16x8*)&XT[tw * 64 + sp * 8];
            }
            #pragma unroll
            for (int mi = 0; mi < 4; ++mi)
                #pragma unroll
                for (int nj = 0; nj < 4; ++nj)
                    acc[mi][nj] = __builtin_amdgcn_mfma_f32_16x16x32_f16(af[mi], bf[nj], acc[mi][nj], 0, 0, 0);
        }
    }
    #pragma unroll
    for (int mi = 0; mi < 4; ++mi) {
        #pragma unroll
        for (int r = 0; r < 4; ++r) {
            int o = mi * 16 + (lane >> 4) * 4 + r;
            if (o < 50) {
                float bv = bc1[o];
                #pragma unroll
                for (int nj = 0; nj < 4; ++nj) {
                    int t = t0 + wn + nj * 16 + (lane & 15);
                    float v = acc[mi][nj][r] + bv;
                    out[(size_t)g * 50 * H + (size_t)o * H + t] = v > 0.f ? v : 0.f;
                }
            }
        }
    }
}

// ---------------- maxpool1d k=3 s=2, merged Z+Y ----------------
__global__ __launch_bounds__(256) void k_pool1(const float* __restrict__ C1Z, const float* __restrict__ C1Y,
                                               float* __restrict__ P1Z, float* __restrict__ P1Y) {
    int b = blockIdx.x;
    const float* in;
    float* out;
    int H, U, go;
    if (b < 12800) { in = C1Z; out = P1Z; H = 1024; U = 511; go = b; }
    else           { in = C1Y; out = P1Y; H = 256;  U = 127; go = b - 12800; }
    const float* p = in + (size_t)go * H;
    float* q = out + (size_t)go * U;
    for (int u = threadIdx.x; u < U; u += 256) {
        float a = p[2 * u], bb = p[2 * u + 1], c = p[2 * u + 2];
        float mm = a > bb ? a : bb;
        q[u] = mm > c ? mm : c;
    }
}

// ---------------- conv2(k=1)+pool(k2s2)+FC+final, ONE block per graph ----------------
__global__ __launch_bounds__(256) void k_c2fc(const float* __restrict__ P1Z, const float* __restrict__ P1Y,
                                              const float* __restrict__ Wc2, const float* __restrict__ bc2,
                                              const float* __restrict__ Wf1, const float* __restrict__ bf1,
                                              const float* __restrict__ Wf2, const float* __restrict__ bf2,
                                              float* __restrict__ out) {
    __shared__ float wL[20][52];
    __shared__ float red[256];
    int g = blockIdx.x, tid = threadIdx.x;
    for (int l = tid; l < 1000; l += 256) wL[l / 50][l % 50] = Wc2[l];
    __syncthreads();
    // ---- Z path (U=511, U2=255) ----
    float s = 0.f;
    if (tid < 255) {
        const float* p = P1Z + (size_t)g * 50 * 511 + 2 * tid;
        float a0[20], a1[20];
        #pragma unroll
        for (int o = 0; o < 20; ++o) { a0[o] = bc2[o]; a1[o] = a0[o]; }
        for (int i = 0; i < 50; ++i) {
            float p0 = p[(size_t)i * 511], p1 = p[(size_t)i * 511 + 1];
            #pragma unroll
            for (int o = 0; o < 20; ++o) {
                a0[o] = fmaf(p0, wL[o][i], a0[o]);
                a1[o] = fmaf(p1, wL[o][i], a1[o]);
            }
        }
        #pragma unroll
        for (int o = 0; o < 20; ++o) {
            float m = a0[o] > a1[o] ? a0[o] : a1[o];
            s = fmaf(m, Wf1[o * 255 + tid], s);
        }
    }
    red[tid] = s;
    __syncthreads();
    for (int off = 128; off > 0; off >>= 1) {
        if (tid < off) red[tid] += red[tid + off];
        __syncthreads();
    }
    float zv = red[0] + bf1[0];
    __syncthreads();
    // ---- Y path (U=127, U2=63) ----
    s = 0.f;
    if (tid < 63) {
        const float* p = P1Y + (size_t)g * 50 * 127 + 2 * tid;
        float a0[20], a1[20];
        #pragma unroll
        for (int o = 0; o < 20; ++o) { a0[o] = bc2[o]; a1[o] = a0[o]; }
        for (int i = 0; i < 50; ++i) {
            float p0 = p[(size_t)i * 127], p1 = p[(size_t)i * 127 + 1];
            #pragma unroll
            for (int o = 0; o < 20; ++o) {
                a0[o] = fmaf(p0, wL[o][i], a0[o]);
                a1[o] = fmaf(p1, wL[o][i], a1[o]);
            }
        }
        #pragma unroll
        for (int o = 0; o < 20; ++o) {
            float m = a0[o] > a1[o] ? a0[o] : a1[o];
            s = fmaf(m, Wf2[o * 63 + tid], s);
        }
    }
    red[tid] = s;
    __syncthreads();
    for (int off = 128; off > 0; off >>= 1) {
        if (tid < off) red[tid] += red[tid + off];
        __syncthreads();
    }
    if (tid == 0) {
        float yv = red[0] + bf2[0];
        float t = zv * yv;
        float pp = 1.f / (1.f + expf(-t));
        pp = fminf(fmaxf(pp, 1e-6f), 1.f - 1e-6f);
        out[2 * g] = 0.f;
        out[2 * g + 1] = logf(pp / (1.f - pp));
    }
}

extern "C" void kernel_launch(void* const* d_in, const int* in_sizes, int n_in,
                              void* d_out, int out_size, void* d_ws, size_t ws_size,
                              hipStream_t stream) {
    const float* x     = (const float*)d_in[0];
    const int*   ei    = (const int*)d_in[1];
    const float* W_in  = (const float*)d_in[2];
    const float* b_in  = (const float*)d_in[3];
    const float* W_g   = (const float*)d_in[4];
    const float* W_ih  = (const float*)d_in[5];
    const float* W_hh  = (const float*)d_in[6];
    const float* b_ih  = (const float*)d_in[7];
    const float* b_hh  = (const float*)d_in[8];
    const float* Wc1   = (const float*)d_in[9];
    const float* bc1   = (const float*)d_in[10];
    const float* Wc2   = (const float*)d_in[11];
    const float* bc2   = (const float*)d_in[12];
    const float* Wf1   = (const float*)d_in[13];
    const float* bf1   = (const float*)d_in[14];
    const float* Wf2   = (const float*)d_in[15];
    const float* bf2   = (const float*)d_in[16];

    float* ws = (float*)d_ws;
    // layout (float units) — identical to rounds 10-13 (verified):
    const size_t OFF_S   = 0;           // S  f16 [N,256] -> 6,553,600
    const size_t OFF_HA  = 6553600;     // HA f16 [N,256] -> 13,107,200
    const size_t OFF_HB  = 13107200;    // HB f16 [N,256] -> 19,660,800
    const size_t OFF_RZ  = 19660800;    // RZ f16 [N,512] -> 32,768,000
    const size_t OFF_XF  = 32768000;    // XF f16 [N,768] -> 52,428,800
    const size_t OFF_WF  = 52428800;    // f16 arena 2,998,272 f16 -> 53,927,936
    const size_t OFF_BRZ = 53927936;    // [512]
    const size_t OFF_BNN = 53928448;    // [512]
    const size_t OFF_INT = 53928960;    // ints 563,201 -> 54,492,161

    _Float16* S  = (_Float16*)(ws + OFF_S);
    _Float16* HA = (_Float16*)(ws + OFF_HA);
    _Float16* HB = (_Float16*)(ws + OFF_HB);
    _Float16* RZ = (_Float16*)(ws + OFF_RZ);
    _Float16* XF = (_Float16*)(ws + OFF_XF);

    _Float16* Win_h = (_Float16*)(ws + OFF_WF);  // [256][768] = 196,608
    _Float16* Wih_h = Win_h + 196608;            // [768][256]
    _Float16* Whh_h = Wih_h + 196608;            // [768][256]
    _Float16* Wg_h  = Whh_h + 196608;            // [6][256][256] = 393,216
    _Float16* Wrz2  = Wg_h  + 393216;            // [6][512][512] = 1,572,864
    _Float16* Wni2  = Wrz2  + 1572864;           // [6][256][256] = 393,216
    _Float16* Wp    = Wni2  + 393216;            // [4][64][192] = 49,152
    _Float16* Whhn  = Whh_h + 512 * 256;         // Whh rows 512..767
    float* brz = ws + OFF_BRZ;
    float* bnn = ws + OFF_BNN;

    int* deg  = (int*)(ws + OFF_INT);
    int* fill = deg + N_NODES;
    int* rowp = fill + N_NODES;
    int* col  = rowp + (N_NODES + 1);

    // conv-phase scratch in DEAD regions (live then: HA, XF, weights, ints):
    float* C1Z = ws + OFF_RZ;            // 13,107,200 -> ends 32,768,000 (== OFF_XF)
    float* P1Z = ws + OFF_HB;            // 6,540,800  -> ends 19,648,000 (< OFF_RZ)
    float* C1Y = ws + OFF_S;             // 3,276,800
    float* P1Y = ws + 3300000;           // 1,625,600  -> ends 4,925,600 (< OFF_HA)

    // ---- mega prep (all elementwise prep + x->XF + deg/fill zeroing, ONE launch) ----
    k_prep<<<42728, 256, 0, stream>>>(W_in, W_ih, W_hh, W_g, x, Wc1, b_ih, b_hh,
                                      Win_h, Wih_h, Whh_h, Wg_h, XF, Wp, brz, bnn, Wrz2,
                                      deg, fill);
    // fold Wg: Wrz2[l][:, :256] = Wih[0:512] @ Wg[l]^T ; Wni2[l] = Wih[512:768] @ Wg[l]^T
    k_gemm2<1, 1, 2, 0><<<48, 256, 0, stream>>>(Wih_h, 256, Wg_h, nullptr,
                                                Wrz2, 512, 256, 8, 0, 65536, 262144, 0);
    k_gemm2<1, 1, 2, 0><<<24, 256, 0, stream>>>(Wih_h + 512 * 256, 256, Wg_h, nullptr,
                                                Wni2, 256, 256, 4, 0, 65536, 65536, 0);

    // ---- CSR build ----
    k_deg<<<N_EDGES / 256, 256, 0, stream>>>(ei, deg);
    k_scan<<<1, 1024, 0, stream>>>(deg, rowp);
    k_fill<<<N_EDGES / 256, 256, 0, stream>>>(ei, rowp, fill, col);

    // ---- h0 = XF @ W_in^T + b_in -> HA (f16) ----
    k_gemm2<1, 1, 2, 1><<<800, 256, 0, stream>>>(XF, FEAT, Win_h, b_in, HA, HID,
                                                 FEAT, 800, 0, 0, 0, 0);

    // ---- GGNN layers (h ping-pongs HA <-> HB; ends in HA) ----
    for (int l = 0; l < 6; ++l) {
        _Float16* hc = (l & 1) ? HB : HA;
        _Float16* hn = (l & 1) ? HA : HB;
        k_agg5<<<6400, 256, 0, stream>>>(rowp, col, hc, S);
        k_gemmrz<<<1600, 256, 0, stream>>>(S, hc, Wrz2 + (size_t)l * 262144, brz, RZ);
        k_nngru<<<800, 512, 0, stream>>>(S, hc, Wni2 + (size_t)l * 65536, Whhn, bnn, RZ, hn);
    }

    // ---- conv head ----
    k_conv1m<<<1280, 256, 0, stream>>>(HA, XF, Wp, bc1, C1Z, C1Y);
    k_pool1<<<25600, 256, 0, stream>>>(C1Z, C1Y, P1Z, P1Y);
    k_c2fc<<<G_GRAPHS, 256, 0, stream>>>(P1Z, P1Y, Wc2, bc2, Wf1, bf1, Wf2, bf2, (float*)d_out);
}

// Round 16
// 1088.269 us; speedup vs baseline: 1.0426x; 1.0125x over previous
//
#include <hip/hip_runtime.h>
#include <math.h>

#define N_NODES 51200
#define N_EDGES 409600
#define FEAT    768
#define HID     256
#define NPG     200
#define G_GRAPHS 256

typedef _Float16 f16x8 __attribute__((ext_vector_type(8)));
typedef _Float16 f16x4 __attribute__((ext_vector_type(4)));
typedef float    f32x4 __attribute__((ext_vector_type(4)));

__device__ __forceinline__ void cvt4(const float* __restrict__ in, _Float16* __restrict__ out, int i) {
    float4 v = *(const float4*)&in[i * 4];
    f16x4 h;
    h[0] = (_Float16)v.x; h[1] = (_Float16)v.y; h[2] = (_Float16)v.z; h[3] = (_Float16)v.w;
    *(f16x4*)&out[i * 4] = h;
}

// ---------------- mega prep: all elementwise prep in ONE launch (incl. x->XF) ----------------
__global__ __launch_bounds__(256) void k_prep(const float* __restrict__ W_in, const float* __restrict__ W_ih,
                                              const float* __restrict__ W_hh, const float* __restrict__ W_g,
                                              const float* __restrict__ x, const float* __restrict__ Wc1,
                                              const float* __restrict__ bih, const float* __restrict__ bhh,
                                              _Float16* __restrict__ Win_h, _Float16* __restrict__ Wih_h,
                                              _Float16* __restrict__ Whh_h, _Float16* __restrict__ Wg_h,
                                              _Float16* __restrict__ XF, _Float16* __restrict__ Wp,
                                              float* __restrict__ brz, float* __restrict__ bnn,
                                              _Float16* __restrict__ Wrz2,
                                              int* __restrict__ deg, int* __restrict__ fill) {
    int id = blockIdx.x * 256 + threadIdx.x;
    if (id < 49152) { cvt4(W_in, Win_h, id); return; }
    id -= 49152;
    if (id < 49152) { cvt4(W_ih, Wih_h, id); return; }
    id -= 49152;
    if (id < 49152) { cvt4(W_hh, Whh_h, id); return; }
    id -= 49152;
    if (id < 98304) { cvt4(W_g, Wg_h, id); return; }
    id -= 98304;
    if (id < 49152) {   // wpack: Wp[ch][o][dk*64+cc]
        int ch = id / 12288, r = id - ch * 12288;
        int o = r / 192, k = r - o * 192;
        int dk = k >> 6, cc = k & 63;
        int c = ch * 64 + cc;
        float v = 0.f;
        if (o < 50 && c < NPG) v = Wc1[(o * NPG + c) * 3 + dk];
        Wp[id] = (_Float16)v;
        return;
    }
    id -= 49152;
    if (id < 1024) {    // biases
        if (id < 512) brz[id] = bih[id] + bhh[id];
        else {
            int q = id - 512;
            bnn[q] = (q < 256) ? bih[512 + q] : bhh[512 + (q - 256)];
        }
        return;
    }
    id -= 1024;
    if (id < 786432) {  // Wrz2 right halves from fp32 W_hh: [l][j][256+c] = Whh[j][c]
        int l = id >> 17, r = id & 131071;
        int j = r >> 8, c = r & 255;
        Wrz2[(size_t)l * 262144 + j * 512 + 256 + c] = (_Float16)W_hh[j * 256 + c];
        return;
    }
    id -= 786432;
    if (id < 12800) { *(int4*)&deg[id * 4] = make_int4(0, 0, 0, 0); return; }
    id -= 12800;
    if (id < 12800) { *(int4*)&fill[id * 4] = make_int4(0, 0, 0, 0); return; }
    id -= 12800;
    if (id < 9830400) { cvt4(x, XF, id); return; }
}

// ---------------- CSR build ----------------
__global__ __launch_bounds__(256) void k_deg(const int* __restrict__ ei, int* __restrict__ deg) {
    int e = blockIdx.x * 256 + threadIdx.x;
    if (e < N_EDGES) atomicAdd(&deg[ei[N_EDGES + e]], 1);
}

__global__ __launch_bounds__(1024) void k_scan(const int* __restrict__ deg, int* __restrict__ rowp) {
    __shared__ int sums[1024];
    int tid = threadIdx.x;
    int base = tid * 50;
    int s = 0;
    for (int j = 0; j < 50; ++j) s += deg[base + j];
    sums[tid] = s;
    __syncthreads();
    for (int off = 1; off < 1024; off <<= 1) {
        int v = 0;
        if (tid >= off) v = sums[tid - off];
        __syncthreads();
        sums[tid] += v;
        __syncthreads();
    }
    int run = sums[tid] - s; // exclusive prefix
    for (int j = 0; j < 50; ++j) { rowp[base + j] = run; run += deg[base + j]; }
    if (tid == 1023) rowp[N_NODES] = run;
}

__global__ __launch_bounds__(256) void k_fill(const int* __restrict__ ei, const int* __restrict__ rowp,
                                              int* __restrict__ fill, int* __restrict__ col) {
    int e = blockIdx.x * 256 + threadIdx.x;
    if (e < N_EDGES) {
        int d = ei[N_EDGES + e];
        int pos = atomicAdd(&fill[d], 1);
        col[rowp[d] + pos] = ei[e];
    }
}

// ---------------- fp16 MFMA GEMM (NT): C[M,*] = A[M,K] @ B_f16[J,K]^T + bias ----------------
template<int AF16, int OUT, int COLB, int SWZ>
__global__ __launch_bounds__(256) void k_gemm2(const void* __restrict__ Av, int lda,
                                               const _Float16* __restrict__ B,
                                               const float* __restrict__ bias,
                                               void* __restrict__ Cv, int ldc,
                                               int K, int wgPerL, int aLStride, int bLStride,
                                               int cLStride, int biasStride) {
    __shared__ _Float16 As[128 * 64];
    __shared__ _Float16 Bs[128 * 64];
    int wg = blockIdx.x;
    int l = wg / wgPerL; wg -= l * wgPerL;
    if (AF16) Av = (const void*)((const _Float16*)Av + (size_t)l * aLStride);
    else      Av = (const void*)((const float*)Av + (size_t)l * aLStride);
    B += (size_t)l * bLStride;
    if (bias) bias += (size_t)l * biasStride;
    if (OUT == 1) Cv = (void*)((_Float16*)Cv + (size_t)l * cLStride);
    else          Cv = (void*)((float*)Cv + (size_t)l * cLStride);
    int rowBase, colBase;
    if (SWZ) {
        int xcd = wg & 7, t = wg >> 3;
        int cb = t % COLB, gidx = t / COLB;
        rowBase = (gidx * 8 + xcd) * 128;
        colBase = cb * 128;
    } else {
        rowBase = (wg / COLB) * 128;
        colBase = (wg % COLB) * 128;
    }
    int tid = threadIdx.x;
    int lane = tid & 63;
    int wid = tid >> 6;
    int wr = wid >> 1, wc = wid & 1;
    f32x4 acc[4][4] = {};
    for (int k0 = 0; k0 < K; k0 += 64) {
        __syncthreads();
        #pragma unroll
        for (int p = 0; p < 4; ++p) {
            int c = p * 256 + tid;
            int row = c >> 3, slot = c & 7;
            int dst = row * 64 + ((slot ^ (row & 7)) * 8);
            if (AF16) {
                const _Float16* srcA = (const _Float16*)Av + (size_t)(rowBase + row) * lda + k0 + slot * 8;
                *(f16x8*)&As[dst] = *(const f16x8*)srcA;
            } else {
                const float* srcA = (const float*)Av + (size_t)(rowBase + row) * lda + k0 + slot * 8;
                float4 f0 = *(const float4*)srcA;
                float4 f1 = *(const float4*)(srcA + 4);
                f16x8 hv;
                hv[0] = (_Float16)f0.x; hv[1] = (_Float16)f0.y; hv[2] = (_Float16)f0.z; hv[3] = (_Float16)f0.w;
                hv[4] = (_Float16)f1.x; hv[5] = (_Float16)f1.y; hv[6] = (_Float16)f1.z; hv[7] = (_Float16)f1.w;
                *(f16x8*)&As[dst] = hv;
            }
            const _Float16* srcB = B + (size_t)(colBase + row) * K + k0 + slot * 8;
            *(f16x8*)&Bs[dst] = *(const f16x8*)srcB;
        }
        __syncthreads();
        #pragma unroll
        for (int ks = 0; ks < 2; ++ks) {
            f16x8 af[4], bf[4];
            #pragma unroll
            for (int mi = 0; mi < 4; ++mi) {
                int row = wr * 64 + mi * 16 + (lane & 15);
                int slot = (lane >> 4) + ks * 4;
                af[mi] = *(const f16x8*)&As[row * 64 + ((slot ^ (row & 7)) * 8)];
            }
            #pragma unroll
            for (int nj = 0; nj < 4; ++nj) {
                int row = wc * 64 + nj * 16 + (lane & 15);
                int slot = (lane >> 4) + ks * 4;
                bf[nj] = *(const f16x8*)&Bs[row * 64 + ((slot ^ (row & 7)) * 8)];
            }
            #pragma unroll
            for (int mi = 0; mi < 4; ++mi)
                #pragma unroll
                for (int nj = 0; nj < 4; ++nj)
                    acc[mi][nj] = __builtin_amdgcn_mfma_f32_16x16x32_f16(af[mi], bf[nj], acc[mi][nj], 0, 0, 0);
        }
    }
    #pragma unroll
    for (int mi = 0; mi < 4; ++mi) {
        #pragma unroll
        for (int nj = 0; nj < 4; ++nj) {
            int col = colBase + wc * 64 + nj * 16 + (lane & 15);
            float bv = bias ? bias[col] : 0.f;
            #pragma unroll
            for (int r = 0; r < 4; ++r) {
                int row = rowBase + wr * 64 + mi * 16 + (lane >> 4) * 4 + r;
                float val = acc[mi][nj][r] + bv;
                if (OUT == 0) ((float*)Cv)[(size_t)row * ldc + col] = val;
                else          ((_Float16*)Cv)[(size_t)row * ldc + col] = (_Float16)val;
            }
        }
    }
}

// ---------------- merged Wg-fold (both fold GEMMs in one launch) ----------------
// blocks 0..47: Wrz2[l][:,0:256] = Wih[0:512] @ Wg[l]^T (8 blocks/layer: 4 row x 2 col)
// blocks 48..71: Wni2[l] = Wih[512:768] @ Wg[l]^T (4 blocks/layer: 2 row x 2 col)
__global__ __launch_bounds__(256) void k_fold(const _Float16* __restrict__ Wih_h,
                                              const _Float16* __restrict__ Wg_h,
                                              _Float16* __restrict__ Wrz2,
                                              _Float16* __restrict__ Wni2) {
    __shared__ _Float16 As[128 * 64];
    __shared__ _Float16 Bs[128 * 64];
    int wg = blockIdx.x;
    const _Float16* Av;
    const _Float16* B;
    _Float16* Cv;
    int ldc;
    if (wg < 48) {
        int l = wg >> 3; wg &= 7;
        Av = Wih_h;
        B  = Wg_h + l * 65536;
        Cv = Wrz2 + (size_t)l * 262144;
        ldc = 512;
    } else {
        wg -= 48;
        int l = wg >> 2; wg &= 3;
        Av = Wih_h + 512 * 256;
        B  = Wg_h + l * 65536;
        Cv = Wni2 + (size_t)l * 65536;
        ldc = 256;
    }
    int rowBase = (wg >> 1) * 128;
    int colBase = (wg & 1) * 128;
    int tid = threadIdx.x;
    int lane = tid & 63;
    int wid = tid >> 6;
    int wr = wid >> 1, wc = wid & 1;
    f32x4 acc[4][4] = {};
    for (int k0 = 0; k0 < 256; k0 += 64) {
        __syncthreads();
        #pragma unroll
        for (int p = 0; p < 4; ++p) {
            int c = p * 256 + tid;
            int row = c >> 3, slot = c & 7;
            int dst = row * 64 + ((slot ^ (row & 7)) * 8);
            *(f16x8*)&As[dst] = *(const f16x8*)&Av[(size_t)(rowBase + row) * 256 + k0 + slot * 8];
            *(f16x8*)&Bs[dst] = *(const f16x8*)&B[(size_t)(colBase + row) * 256 + k0 + slot * 8];
        }
        __syncthreads();
        #pragma unroll
        for (int ks = 0; ks < 2; ++ks) {
            f16x8 af[4], bf[4];
            #pragma unroll
            for (int mi = 0; mi < 4; ++mi) {
                int row = wr * 64 + mi * 16 + (lane & 15);
                int slot = (lane >> 4) + ks * 4;
                af[mi] = *(const f16x8*)&As[row * 64 + ((slot ^ (row & 7)) * 8)];
            }
            #pragma unroll
            for (int nj = 0; nj < 4; ++nj) {
                int row = wc * 64 + nj * 16 + (lane & 15);
                int slot = (lane >> 4) + ks * 4;
                bf[nj] = *(const f16x8*)&Bs[row * 64 + ((slot ^ (row & 7)) * 8)];
            }
            #pragma unroll
            for (int mi = 0; mi < 4; ++mi)
                #pragma unroll
                for (int nj = 0; nj < 4; ++nj)
                    acc[mi][nj] = __builtin_amdgcn_mfma_f32_16x16x32_f16(af[mi], bf[nj], acc[mi][nj], 0, 0, 0);
        }
    }
    #pragma unroll
    for (int mi = 0; mi < 4; ++mi) {
        #pragma unroll
        for (int nj = 0; nj < 4; ++nj) {
            int col = colBase + wc * 64 + nj * 16 + (lane & 15);
            #pragma unroll
            for (int r = 0; r < 4; ++r) {
                int row = rowBase + wr * 64 + mi * 16 + (lane >> 4) * 4 + r;
                Cv[(size_t)row * ldc + col] = (_Float16)acc[mi][nj][r];
            }
        }
    }
}

// ---------------- rz GEMM: RZ[N,512] = [S|hc] @ Wrz2_l^T + brz (K=512, dual-A) ----------------
__global__ __launch_bounds__(256) void k_gemmrz(const _Float16* __restrict__ S, const _Float16* __restrict__ hc,
                                                const _Float16* __restrict__ B, const float* __restrict__ bias,
                                                _Float16* __restrict__ C) {
    __shared__ _Float16 As[128 * 64];
    __shared__ _Float16 Bs[128 * 64];
    int wg = blockIdx.x;                 // 1600 = 8 * 4 * 50
    int xcd = wg & 7, t = wg >> 3;
    int cb = t % 4, gidx = t / 4;
    int rowBase = (gidx * 8 + xcd) * 128;
    int colBase = cb * 128;
    int tid = threadIdx.x;
    int lane = tid & 63;
    int wid = tid >> 6;
    int wr = wid >> 1, wc = wid & 1;
    f32x4 acc[4][4] = {};
    for (int k0 = 0; k0 < 512; k0 += 64) {
        const _Float16* Abase = (k0 < 256) ? S : hc;
        int kk = k0 & 255;
        __syncthreads();
        #pragma unroll
        for (int p = 0; p < 4; ++p) {
            int c = p * 256 + tid;
            int row = c >> 3, slot = c & 7;
            int dst = row * 64 + ((slot ^ (row & 7)) * 8);
            *(f16x8*)&As[dst] = *(const f16x8*)&Abase[(size_t)(rowBase + row) * 256 + kk + slot * 8];
            *(f16x8*)&Bs[dst] = *(const f16x8*)&B[(size_t)(colBase + row) * 512 + k0 + slot * 8];
        }
        __syncthreads();
        #pragma unroll
        for (int ks = 0; ks < 2; ++ks) {
            f16x8 af[4], bf[4];
            #pragma unroll
            for (int mi = 0; mi < 4; ++mi) {
                int row = wr * 64 + mi * 16 + (lane & 15);
                int slot = (lane >> 4) + ks * 4;
                af[mi] = *(const f16x8*)&As[row * 64 + ((slot ^ (row & 7)) * 8)];
            }
            #pragma unroll
            for (int nj = 0; nj < 4; ++nj) {
                int row = wc * 64 + nj * 16 + (lane & 15);
                int slot = (lane >> 4) + ks * 4;
                bf[nj] = *(const f16x8*)&Bs[row * 64 + ((slot ^ (row & 7)) * 8)];
            }
            #pragma unroll
            for (int mi = 0; mi < 4; ++mi)
                #pragma unroll
                for (int nj = 0; nj < 4; ++nj)
                    acc[mi][nj] = __builtin_amdgcn_mfma_f32_16x16x32_f16(af[mi], bf[nj], acc[mi][nj], 0, 0, 0);
        }
    }
    #pragma unroll
    for (int mi = 0; mi < 4; ++mi) {
        #pragma unroll
        for (int nj = 0; nj < 4; ++nj) {
            int col = colBase + wc * 64 + nj * 16 + (lane & 15);
            float bv = bias[col];
            #pragma unroll
            for (int r = 0; r < 4; ++r) {
                int row = rowBase + wr * 64 + mi * 16 + (lane >> 4) * 4 + r;
                C[(size_t)row * 512 + col] = (_Float16)(acc[mi][nj][r] + bv);
            }
        }
    }
}

// ---------------- fused n-gate GEMMs + GRU ----------------
__global__ __launch_bounds__(512) void k_nngru(const _Float16* __restrict__ S, const _Float16* __restrict__ hc,
                                               const _Float16* __restrict__ B0, const _Float16* __restrict__ B1,
                                               const float* __restrict__ bnn, const _Float16* __restrict__ rz,
                                               _Float16* __restrict__ hn) {
    __shared__ _Float16 As0[128 * 64], As1[128 * 64], Bs0[128 * 64], Bs1[128 * 64];
    int wg = blockIdx.x;                 // 800 = 8 * 2 * 50
    int xcd = wg & 7, t = wg >> 3;
    int cb = t % 2, gidx = t / 2;
    int rowBase = (gidx * 8 + xcd) * 128;
    int colBase = cb * 128;
    int tid = threadIdx.x;
    int lane = tid & 63;
    int wid = tid >> 6;
    int wr = wid >> 2, wc = wid & 3;
    f32x4 acc0[4][2] = {}, acc1[4][2] = {};
    for (int k0 = 0; k0 < 256; k0 += 64) {
        __syncthreads();
        #pragma unroll
        for (int p = 0; p < 8; ++p) {
            int q = p * 512 + tid;
            int tile = q >> 10;
            int c = q & 1023;
            int row = c >> 3, slot = c & 7;
            int dst = row * 64 + ((slot ^ (row & 7)) * 8);
            const _Float16* src;
            _Float16* d;
            if (tile == 0)      { src = S  + (size_t)(rowBase + row) * 256 + k0 + slot * 8; d = As0; }
            else if (tile == 1) { src = hc + (size_t)(rowBase + row) * 256 + k0 + slot * 8; d = As1; }
            else if (tile == 2) { src = B0 + (size_t)(colBase + row) * 256 + k0 + slot * 8; d = Bs0; }
            else                { src = B1 + (size_t)(colBase + row) * 256 + k0 + slot * 8; d = Bs1; }
            *(f16x8*)&d[dst] = *(const f16x8*)src;
        }
        __syncthreads();
        #pragma unroll
        for (int ks = 0; ks < 2; ++ks) {
            f16x8 a0[4], a1[4], b0[2], b1[2];
            #pragma unroll
            for (int mi = 0; mi < 4; ++mi) {
                int row = wr * 64 + mi * 16 + (lane & 15);
                int slot = (lane >> 4) + ks * 4;
                int off = row * 64 + ((slot ^ (row & 7)) * 8);
                a0[mi] = *(const f16x8*)&As0[off];
                a1[mi] = *(const f16x8*)&As1[off];
            }
            #pragma unroll
            for (int nj = 0; nj < 2; ++nj) {
                int row = wc * 32 + nj * 16 + (lane & 15);
                int slot = (lane >> 4) + ks * 4;
                int off = row * 64 + ((slot ^ (row & 7)) * 8);
                b0[nj] = *(const f16x8*)&Bs0[off];
                b1[nj] = *(const f16x8*)&Bs1[off];
            }
            #pragma unroll
            for (int mi = 0; mi < 4; ++mi)
                #pragma unroll
                for (int nj = 0; nj < 2; ++nj) {
                    acc0[mi][nj] = __builtin_amdgcn_mfma_f32_16x16x32_f16(a0[mi], b0[nj], acc0[mi][nj], 0, 0, 0);
                    acc1[mi][nj] = __builtin_amdgcn_mfma_f32_16x16x32_f16(a1[mi], b1[nj], acc1[mi][nj], 0, 0, 0);
                }
        }
    }
    #pragma unroll
    for (int mi = 0; mi < 4; ++mi) {
        #pragma unroll
        for (int nj = 0; nj < 2; ++nj) {
            int col = colBase + wc * 32 + nj * 16 + (lane & 15);
            float bi = bnn[col], bh = bnn[256 + col];
            #pragma unroll
            for (int r = 0; r < 4; ++r) {
                int row = rowBase + wr * 64 + mi * 16 + (lane >> 4) * 4 + r;
                float rv = (float)rz[(size_t)row * 512 + col];
                float zv = (float)rz[(size_t)row * 512 + 256 + col];
                float rg = 1.f / (1.f + expf(-rv));
                float zg = 1.f / (1.f + expf(-zv));
                float ng = tanhf((acc0[mi][nj][r] + bi) + rg * (acc1[mi][nj][r] + bh));
                float ho = (float)hc[(size_t)row * 256 + col];
                hn[(size_t)row * 256 + col] = (_Float16)((1.f - zg) * ng + zg * ho);
            }
        }
    }
}

// ---------------- gather-sum of hc into S (32 lanes/node, f16x8 loads, unroll 4) ----------------
__global__ __launch_bounds__(256) void k_agg5(const int* __restrict__ rowp, const int* __restrict__ col,
                                              const _Float16* __restrict__ hc, _Float16* __restrict__ S) {
    int v = blockIdx.x * 8 + (threadIdx.x >> 5);
    int lane = threadIdx.x & 31;
    int beg = rowp[v], end = rowp[v + 1];
    const _Float16* hf = hc + lane * 8;
    float a0 = 0.f, a1 = 0.f, a2 = 0.f, a3 = 0.f, a4 = 0.f, a5 = 0.f, a6 = 0.f, a7 = 0.f;
    int i = beg;
    for (; i + 3 < end; i += 4) {
        int c0 = col[i], c1 = col[i + 1], c2 = col[i + 2], c3 = col[i + 3];
        f16x8 u0 = *(const f16x8*)&hf[(size_t)c0 * 256];
        f16x8 u1 = *(const f16x8*)&hf[(size_t)c1 * 256];
        f16x8 u2 = *(const f16x8*)&hf[(size_t)c2 * 256];
        f16x8 u3 = *(const f16x8*)&hf[(size_t)c3 * 256];
        a0 += ((float)u0[0] + (float)u1[0]) + ((float)u2[0] + (float)u3[0]);
        a1 += ((float)u0[1] + (float)u1[1]) + ((float)u2[1] + (float)u3[1]);
        a2 += ((float)u0[2] + (float)u1[2]) + ((float)u2[2] + (float)u3[2]);
        a3 += ((float)u0[3] + (float)u1[3]) + ((float)u2[3] + (float)u3[3]);
        a4 += ((float)u0[4] + (float)u1[4]) + ((float)u2[4] + (float)u3[4]);
        a5 += ((float)u0[5] + (float)u1[5]) + ((float)u2[5] + (float)u3[5]);
        a6 += ((float)u0[6] + (float)u1[6]) + ((float)u2[6] + (float)u3[6]);
        a7 += ((float)u0[7] + (float)u1[7]) + ((float)u2[7] + (float)u3[7]);
    }
    for (; i < end; ++i) {
        f16x8 u = *(const f16x8*)&hf[(size_t)col[i] * 256];
        a0 += (float)u[0]; a1 += (float)u[1]; a2 += (float)u[2]; a3 += (float)u[3];
        a4 += (float)u[4]; a5 += (float)u[5]; a6 += (float)u[6]; a7 += (float)u[7];
    }
    f16x8 o;
    o[0] = (_Float16)a0; o[1] = (_Float16)a1; o[2] = (_Float16)a2; o[3] = (_Float16)a3;
    o[4] = (_Float16)a4; o[5] = (_Float16)a5; o[6] = (_Float16)a6; o[7] = (_Float16)a7;
    *(f16x8*)&S[(size_t)v * 256 + lane * 8] = o;
}

// ---------------- conv1 as MFMA implicit GEMM, merged Z+Y launch (f16 inputs) ----------------
__global__ __launch_bounds__(256, 2) void k_conv1m(const _Float16* __restrict__ hf, const _Float16* __restrict__ xf,
                                                   const _Float16* __restrict__ Wp, const float* __restrict__ bc1,
                                                   float* __restrict__ outZ, float* __restrict__ outY) {
    __shared__ _Float16 XT[272 * 64];
    __shared__ _Float16 WL[64 * 192];
    int b = blockIdx.x;
    int g, t0, H;
    float* out;
    if (b < 1024) { g = b >> 2; t0 = (b & 3) * 256; H = 1024; out = outZ; }
    else          { g = b - 1024; t0 = 0; H = 256; out = outY; }
    int tid = threadIdx.x;
    int lane = tid & 63;
    int wn = (tid >> 6) * 64;
    f32x4 acc[4][4] = {};
    for (int ch = 0; ch < 4; ++ch) {
        __syncthreads();
        #pragma unroll
        for (int i = 0; i < 6; ++i) {
            int q = i * 256 + tid;
            int o = q / 24, sk = q - o * 24;
            int skp = (sk & 0x18) | ((sk & 7) ^ (o & 7));
            *(f16x8*)&WL[o * 192 + skp * 8] = *(const f16x8*)&Wp[ch * 12288 + o * 192 + sk * 8];
        }
        for (int u = tid; u < 272; u += 256) {
            int r8 = u / 34, pc = u - r8 * 34;
            int gstart = t0 - 8 + pc * 8;
            int c0 = r8 * 8;
            f16x8 zv;
            #pragma unroll
            for (int q = 0; q < 8; ++q) zv[q] = (_Float16)0.f;
            f16x8 rows[8];
            if (gstart < 0 || gstart >= H) {
                #pragma unroll
                for (int j = 0; j < 8; ++j) rows[j] = zv;
            } else {
                const _Float16* base;
                int stride;
                if (gstart < HID) { base = hf + gstart; stride = 256; }
                else              { base = xf + (gstart - HID); stride = 768; }
                int node0 = g * NPG + ch * 64 + c0;
                #pragma unroll
                for (int j = 0; j < 8; ++j) {
                    int cg = ch * 64 + c0 + j;
                    rows[j] = (cg < NPG) ? *(const f16x8*)&base[(size_t)(node0 + j) * stride] : zv;
                }
            }
            #pragma unroll
            for (int jj = 0; jj < 8; ++jj) {
                f16x8 w;
                #pragma unroll
                for (int j = 0; j < 8; ++j) w[j] = rows[j][jj];
                int p = pc * 8 + jj;
                int slot = r8 ^ jj ^ (pc & 7);
                *(f16x8*)&XT[p * 64 + slot * 8] = w;
            }
        }
        __syncthreads();
        #pragma unroll
        for (int ks = 0; ks < 6; ++ks) {
            int dk = ks >> 1, cs0 = (ks & 1) << 2;
            f16x8 af[4], bf[4];
            #pragma unroll
            for (int mi = 0; mi < 4; ++mi) {
                int o = mi * 16 + (lane & 15);
                int sk = ks * 4 + (lane >> 4);
                int skp = (sk & 0x18) | ((sk & 7) ^ (o & 7));
                af[mi] = *(const f16x8*)&WL[o * 192 + skp * 8];
            }
            #pragma unroll
            for (int nj = 0; nj < 4; ++nj) {
                int tw = wn + nj * 16 + (lane & 15) + dk + 7;
                int sp = (cs0 + (lane >> 4)) ^ (tw & 7) ^ ((tw >> 3) & 7);
                bf[nj] = *(const f16x8*)&XT[tw * 64 + sp * 8];
            }
            #pragma unroll
            for (int mi = 0; mi < 4; ++mi)
                #pragma unroll
                for (int nj = 0; nj < 4; ++nj)
                    acc[mi][nj] = __builtin_amdgcn_mfma_f32_16x16x32_f16(af[mi], bf[nj], acc[mi][nj], 0, 0, 0);
        }
    }
    #pragma unroll
    for (int mi = 0; mi < 4; ++mi) {
        #pragma unroll
        for (int r = 0; r < 4; ++r) {
            int o = mi * 16 + (lane >> 4) * 4 + r;
            if (o < 50) {
                float bv = bc1[o];
                #pragma unroll
                for (int nj = 0; nj < 4; ++nj) {
                    int t = t0 + wn + nj * 16 + (lane & 15);
                    float v = acc[mi][nj][r] + bv;
                    out[(size_t)g * 50 * H + (size_t)o * H + t] = v > 0.f ? v : 0.f;
                }
            }
        }
    }
}

// ---------------- pool1 + conv2(k=1) + pool2 + FC + final, ONE block per graph ----------------
// Reads conv1 output directly; P1[u] = max3(C1[2u..2u+2]) computed inline (bit-identical).
__global__ __launch_bounds__(256) void k_c2fc(const float* __restrict__ C1Z, const float* __restrict__ C1Y,
                                              const float* __restrict__ Wc2, const float* __restrict__ bc2,
                                              const float* __restrict__ Wf1, const float* __restrict__ bf1,
                                              const float* __restrict__ Wf2, const float* __restrict__ bf2,
                                              float* __restrict__ out) {
    __shared__ float wL[20][52];
    __shared__ float red[256];
    int g = blockIdx.x, tid = threadIdx.x;
    for (int l = tid; l < 1000; l += 256) wL[l / 50][l % 50] = Wc2[l];
    __syncthreads();
    // ---- Z path (H=1024, U=511, U2=255) ----
    float s = 0.f;
    if (tid < 255) {
        const float* p = C1Z + (size_t)g * 50 * 1024 + 4 * tid;
        float a0[20], a1[20];
        #pragma unroll
        for (int o = 0; o < 20; ++o) { a0[o] = bc2[o]; a1[o] = a0[o]; }
        for (int i = 0; i < 50; ++i) {
            const float* r = p + (size_t)i * 1024;
            float c0 = r[0], c1 = r[1], c2v = r[2], c3 = r[3], c4 = r[4];
            float m01 = c0 > c1 ? c0 : c1;
            float p0 = m01 > c2v ? m01 : c2v;
            float m23 = c2v > c3 ? c2v : c3;
            float p1 = m23 > c4 ? m23 : c4;
            #pragma unroll
            for (int o = 0; o < 20; ++o) {
                a0[o] = fmaf(p0, wL[o][i], a0[o]);
                a1[o] = fmaf(p1, wL[o][i], a1[o]);
            }
        }
        #pragma unroll
        for (int o = 0; o < 20; ++o) {
            float m = a0[o] > a1[o] ? a0[o] : a1[o];
            s = fmaf(m, Wf1[o * 255 + tid], s);
        }
    }
    red[tid] = s;
    __syncthreads();
    for (int off = 128; off > 0; off >>= 1) {
        if (tid < off) red[tid] += red[tid + off];
        __syncthreads();
    }
    float zv = red[0] + bf1[0];
    __syncthreads();
    // ---- Y path (H=256, U=127, U2=63) ----
    s = 0.f;
    if (tid < 63) {
        const float* p = C1Y + (size_t)g * 50 * 256 + 4 * tid;
        float a0[20], a1[20];
        #pragma unroll
        for (int o = 0; o < 20; ++o) { a0[o] = bc2[o]; a1[o] = a0[o]; }
        for (int i = 0; i < 50; ++i) {
            const float* r = p + (size_t)i * 256;
            float c0 = r[0], c1 = r[1], c2v = r[2], c3 = r[3], c4 = r[4];
            float m01 = c0 > c1 ? c0 : c1;
            float p0 = m01 > c2v ? m01 : c2v;
            float m23 = c2v > c3 ? c2v : c3;
            float p1 = m23 > c4 ? m23 : c4;
            #pragma unroll
            for (int o = 0; o < 20; ++o) {
                a0[o] = fmaf(p0, wL[o][i], a0[o]);
                a1[o] = fmaf(p1, wL[o][i], a1[o]);
            }
        }
        #pragma unroll
        for (int o = 0; o < 20; ++o) {
            float m = a0[o] > a1[o] ? a0[o] : a1[o];
            s = fmaf(m, Wf2[o * 63 + tid], s);
        }
    }
    red[tid] = s;
    __syncthreads();
    for (int off = 128; off > 0; off >>= 1) {
        if (tid < off) red[tid] += red[tid + off];
        __syncthreads();
    }
    if (tid == 0) {
        float yv = red[0] + bf2[0];
        float t = zv * yv;
        float pp = 1.f / (1.f + expf(-t));
        pp = fminf(fmaxf(pp, 1e-6f), 1.f - 1e-6f);
        out[2 * g] = 0.f;
        out[2 * g + 1] = logf(pp / (1.f - pp));
    }
}

extern "C" void kernel_launch(void* const* d_in, const int* in_sizes, int n_in,
                              void* d_out, int out_size, void* d_ws, size_t ws_size,
                              hipStream_t stream) {
    const float* x     = (const float*)d_in[0];
    const int*   ei    = (const int*)d_in[1];
    const float* W_in  = (const float*)d_in[2];
    const float* b_in  = (const float*)d_in[3];
    const float* W_g   = (const float*)d_in[4];
    const float* W_ih  = (const float*)d_in[5];
    const float* W_hh  = (const float*)d_in[6];
    const float* b_ih  = (const float*)d_in[7];
    const float* b_hh  = (const float*)d_in[8];
    const float* Wc1   = (const float*)d_in[9];
    const float* bc1   = (const float*)d_in[10];
    const float* Wc2   = (const float*)d_in[11];
    const float* bc2   = (const float*)d_in[12];
    const float* Wf1   = (const float*)d_in[13];
    const float* bf1   = (const float*)d_in[14];
    const float* Wf2   = (const float*)d_in[15];
    const float* bf2   = (const float*)d_in[16];

    float* ws = (float*)d_ws;
    // layout (float units) — identical to rounds 10-15 (verified):
    const size_t OFF_S   = 0;           // S  f16 [N,256] -> 6,553,600
    const size_t OFF_HA  = 6553600;     // HA f16 [N,256] -> 13,107,200
    const size_t OFF_HB  = 13107200;    // HB f16 [N,256] -> 19,660,800
    const size_t OFF_RZ  = 19660800;    // RZ f16 [N,512] -> 32,768,000
    const size_t OFF_XF  = 32768000;    // XF f16 [N,768] -> 52,428,800
    const size_t OFF_WF  = 52428800;    // f16 arena 2,998,272 f16 -> 53,927,936
    const size_t OFF_BRZ = 53927936;    // [512]
    const size_t OFF_BNN = 53928448;    // [512]
    const size_t OFF_INT = 53928960;    // ints 563,201 -> 54,492,161

    _Float16* S  = (_Float16*)(ws + OFF_S);
    _Float16* HA = (_Float16*)(ws + OFF_HA);
    _Float16* HB = (_Float16*)(ws + OFF_HB);
    _Float16* RZ = (_Float16*)(ws + OFF_RZ);
    _Float16* XF = (_Float16*)(ws + OFF_XF);

    _Float16* Win_h = (_Float16*)(ws + OFF_WF);  // [256][768] = 196,608
    _Float16* Wih_h = Win_h + 196608;            // [768][256]
    _Float16* Whh_h = Wih_h + 196608;            // [768][256]
    _Float16* Wg_h  = Whh_h + 196608;            // [6][256][256] = 393,216
    _Float16* Wrz2  = Wg_h  + 393216;            // [6][512][512] = 1,572,864
    _Float16* Wni2  = Wrz2  + 1572864;           // [6][256][256] = 393,216
    _Float16* Wp    = Wni2  + 393216;            // [4][64][192] = 49,152
    _Float16* Whhn  = Whh_h + 512 * 256;         // Whh rows 512..767
    float* brz = ws + OFF_BRZ;
    float* bnn = ws + OFF_BNN;

    int* deg  = (int*)(ws + OFF_INT);
    int* fill = deg + N_NODES;
    int* rowp = fill + N_NODES;
    int* col  = rowp + (N_NODES + 1);

    // conv-phase scratch in DEAD regions (live then: HA, XF, weights, ints):
    float* C1Z = ws + OFF_RZ;            // 13,107,200 -> ends 32,768,000 (== OFF_XF)
    float* C1Y = ws + OFF_S;             // 3,276,800  (S dead after GGNN loop)

    // ---- mega prep (all elementwise prep + x->XF + deg/fill zeroing, ONE launch) ----
    k_prep<<<42728, 256, 0, stream>>>(W_in, W_ih, W_hh, W_g, x, Wc1, b_ih, b_hh,
                                      Win_h, Wih_h, Whh_h, Wg_h, XF, Wp, brz, bnn, Wrz2,
                                      deg, fill);
    // fold Wg into gate weights (both folds, one launch)
    k_fold<<<72, 256, 0, stream>>>(Wih_h, Wg_h, Wrz2, Wni2);

    // ---- CSR build ----
    k_deg<<<N_EDGES / 256, 256, 0, stream>>>(ei, deg);
    k_scan<<<1, 1024, 0, stream>>>(deg, rowp);
    k_fill<<<N_EDGES / 256, 256, 0, stream>>>(ei, rowp, fill, col);

    // ---- h0 = XF @ W_in^T + b_in -> HA (f16) ----
    k_gemm2<1, 1, 2, 1><<<800, 256, 0, stream>>>(XF, FEAT, Win_h, b_in, HA, HID,
                                                 FEAT, 800, 0, 0, 0, 0);

    // ---- GGNN layers (h ping-pongs HA <-> HB; ends in HA) ----
    for (int l = 0; l < 6; ++l) {
        _Float16* hc = (l & 1) ? HB : HA;
        _Float16* hn = (l & 1) ? HA : HB;
        k_agg5<<<6400, 256, 0, stream>>>(rowp, col, hc, S);
        k_gemmrz<<<1600, 256, 0, stream>>>(S, hc, Wrz2 + (size_t)l * 262144, brz, RZ);
        k_nngru<<<800, 512, 0, stream>>>(S, hc, Wni2 + (size_t)l * 65536, Whhn, bnn, RZ, hn);
    }

    // ---- conv head (pool1 fused into c2fc) ----
    k_conv1m<<<1280, 256, 0, stream>>>(HA, XF, Wp, bc1, C1Z, C1Y);
    k_c2fc<<<G_GRAPHS, 256, 0, stream>>>(C1Z, C1Y, Wc2, bc2, Wf1, bf1, Wf2, bf2, (float*)d_out);
}